// Round 5
// baseline (217.553 us; speedup 1.0000x reference)
//
#include <hip/hip_runtime.h>
#include <stdint.h>

#define DM 1024
#define HEADS 16
#define DH 64
#define BQ 4
#define TT 2048
#define MTOT (BQ*TT)  // 8192
#define NQT (TT/64)   // 32 q-tiles per (b,h)

typedef __attribute__((ext_vector_type(8))) __bf16 bf16x8;
typedef __attribute__((ext_vector_type(4))) float f32x4;
typedef __attribute__((ext_vector_type(4))) uint32_t u32x4;
typedef unsigned short u16;
typedef __attribute__((ext_vector_type(8))) unsigned short u16x8;

__device__ __forceinline__ u16 f2b(float f) {
  uint32_t u = __builtin_bit_cast(uint32_t, f);
  u = (u + 0x7fffu + ((u >> 16) & 1u)) >> 16;
  return (u16)u;
}

__device__ __forceinline__ uint32_t cvtpk(float lo, float hi) {
  uint32_t r;
  asm("v_cvt_pk_bf16_f32 %0, %1, %2" : "=v"(r) : "v"(lo), "v"(hi));
  return r;
}

__device__ __forceinline__ void gload_lds16(const u16* g, u16* l) {
  __builtin_amdgcn_global_load_lds(
      (const __attribute__((address_space(1))) void*)g,
      (__attribute__((address_space(3))) void*)l, 16, 0, 0);
}

// ---------------- cast fp32 -> bf16 (vectorized) ----------------
__global__ __launch_bounds__(256) void cast_f32_bf16(const float* __restrict__ in,
                                                     u16* __restrict__ out, int n4) {
  int i = blockIdx.x * 256 + threadIdx.x;
  if (i >= n4) return;
  float4 v = ((const float4*)in)[i];
  ushort4 o;
  o.x = f2b(v.x); o.y = f2b(v.y); o.z = f2b(v.z); o.w = f2b(v.w);
  ((ushort4*)out)[i] = o;
}

// cast three weight matrices into one contiguous [3*DM][DM] bf16 buffer
__global__ __launch_bounds__(256) void cast_w3(const float* __restrict__ W0,
                                               const float* __restrict__ W1,
                                               const float* __restrict__ W2,
                                               u16* __restrict__ out) {
  const int per = DM * DM / 4;  // float4s per matrix
  int i = blockIdx.x * 256 + threadIdx.x;
  const float* src = (i < per) ? W0 : (i < 2 * per) ? W1 : W2;
  int li = (i < per) ? i : (i < 2 * per) ? (i - per) : (i - 2 * per);
  float4 v = ((const float4*)src)[li];
  ushort4 o;
  o.x = f2b(v.x); o.y = f2b(v.y); o.z = f2b(v.z); o.w = f2b(v.w);
  ((ushort4*)out)[i] = o;
}

// ---------------- fused QKV GEMM over N=3072 ----------------
__global__ __launch_bounds__(256) void gemm_qkv(const u16* __restrict__ A,
                                                const u16* __restrict__ Wqkv,
                                                const float* __restrict__ bq,
                                                const float* __restrict__ bk,
                                                const float* __restrict__ bv,
                                                u16* __restrict__ Qo,
                                                u16* __restrict__ Ko,
                                                u16* __restrict__ Vto,
                                                float qs) {
  __shared__ u16 As[128 * 32];
  __shared__ u16 Bs[128 * 32];
  const int tid = threadIdx.x;
  const int lane = tid & 63, wave = tid >> 6;
  const int wr = wave >> 1, wc = wave & 1;
  const int m0 = blockIdx.y * 128, n0 = blockIdx.x * 128;

  f32x4 acc[4][4];
#pragma unroll
  for (int m = 0; m < 4; ++m)
#pragma unroll
    for (int n = 0; n < 4; ++n) acc[m][n] = (f32x4){0.f, 0.f, 0.f, 0.f};

  const int srow = wave * 32 + (lane >> 2);
  const int scol = (lane & 3) * 8;
  const u16* gA = A + (size_t)(m0 + srow) * DM + scol;
  const u16* gB = Wqkv + (size_t)(n0 + srow) * DM + scol;
  u16* lA = &As[wave * 32 * 32];
  u16* lB = &Bs[wave * 32 * 32];
  const int fr = lane & 15;
  const int k8 = (lane >> 4) * 8;

  for (int k0 = 0; k0 < DM; k0 += 32) {
    __syncthreads();
    gload_lds16(gA + k0, lA);
    gload_lds16(gA + k0 + 16 * DM, lA + 16 * 32);
    gload_lds16(gB + k0, lB);
    gload_lds16(gB + k0 + 16 * DM, lB + 16 * 32);
    __syncthreads();
    bf16x8 af[4], bfr[4];
#pragma unroll
    for (int m = 0; m < 4; ++m)
      af[m] = *(const bf16x8*)&As[(wr * 64 + m * 16 + fr) * 32 + k8];
#pragma unroll
    for (int n = 0; n < 4; ++n)
      bfr[n] = *(const bf16x8*)&Bs[(wc * 64 + n * 16 + fr) * 32 + k8];
#pragma unroll
    for (int m = 0; m < 4; ++m)
#pragma unroll
      for (int n = 0; n < 4; ++n)
        acc[m][n] = __builtin_amdgcn_mfma_f32_16x16x32_bf16(af[m], bfr[n], acc[m][n], 0, 0, 0);
  }

#pragma unroll
  for (int m = 0; m < 4; ++m) {
    const int rg = m0 + wr * 64 + m * 16 + (lane >> 4) * 4;
#pragma unroll
    for (int n = 0; n < 4; ++n) {
      const int cg = n0 + wc * 64 + n * 16 + fr;
      const int seg = cg >> 10, cgl = cg & 1023;
      const float bb = (seg == 0 ? bq : seg == 1 ? bk : bv)[cgl];
      const int hh = cgl >> 6, d = cgl & 63;
      const int bi = rg >> 11, t0 = rg & 2047;
      if (seg == 0) {
#pragma unroll
        for (int j = 0; j < 4; ++j)
          Qo[(((size_t)bi * HEADS + hh) * TT + t0 + j) * DH + d] = f2b((acc[m][n][j] + bb) * qs);
      } else if (seg == 1) {
#pragma unroll
        for (int j = 0; j < 4; ++j)
          Ko[(((size_t)bi * HEADS + hh) * TT + t0 + j) * DH + d] = f2b(acc[m][n][j] + bb);
      } else {
        ushort4 o;
        o.x = f2b(acc[m][n][0] + bb);
        o.y = f2b(acc[m][n][1] + bb);
        o.z = f2b(acc[m][n][2] + bb);
        o.w = f2b(acc[m][n][3] + bb);
        *(ushort4*)&Vto[(((size_t)bi * HEADS + hh) * DH + d) * TT + t0] = o;
      }
    }
  }
}

// ---------------- O-projection GEMM: f32 out [M, DM] ----------------
__global__ __launch_bounds__(256) void gemm_out(const u16* __restrict__ A,
                                                const u16* __restrict__ Bw,
                                                const float* __restrict__ bias,
                                                float* __restrict__ outp) {
  __shared__ u16 As[128 * 32];
  __shared__ u16 Bs[128 * 32];
  const int tid = threadIdx.x;
  const int lane = tid & 63, wave = tid >> 6;
  const int wr = wave >> 1, wc = wave & 1;
  const int m0 = blockIdx.y * 128, n0 = blockIdx.x * 128;

  f32x4 acc[4][4];
#pragma unroll
  for (int m = 0; m < 4; ++m)
#pragma unroll
    for (int n = 0; n < 4; ++n) acc[m][n] = (f32x4){0.f, 0.f, 0.f, 0.f};

  const int srow = wave * 32 + (lane >> 2);
  const int scol = (lane & 3) * 8;
  const u16* gA = A + (size_t)(m0 + srow) * DM + scol;
  const u16* gB = Bw + (size_t)(n0 + srow) * DM + scol;
  u16* lA = &As[wave * 32 * 32];
  u16* lB = &Bs[wave * 32 * 32];
  const int fr = lane & 15;
  const int k8 = (lane >> 4) * 8;

  for (int k0 = 0; k0 < DM; k0 += 32) {
    __syncthreads();
    gload_lds16(gA + k0, lA);
    gload_lds16(gA + k0 + 16 * DM, lA + 16 * 32);
    gload_lds16(gB + k0, lB);
    gload_lds16(gB + k0 + 16 * DM, lB + 16 * 32);
    __syncthreads();
    bf16x8 af[4], bfr[4];
#pragma unroll
    for (int m = 0; m < 4; ++m)
      af[m] = *(const bf16x8*)&As[(wr * 64 + m * 16 + fr) * 32 + k8];
#pragma unroll
    for (int n = 0; n < 4; ++n)
      bfr[n] = *(const bf16x8*)&Bs[(wc * 64 + n * 16 + fr) * 32 + k8];
#pragma unroll
    for (int m = 0; m < 4; ++m)
#pragma unroll
      for (int n = 0; n < 4; ++n)
        acc[m][n] = __builtin_amdgcn_mfma_f32_16x16x32_bf16(af[m], bfr[n], acc[m][n], 0, 0, 0);
  }

#pragma unroll
  for (int m = 0; m < 4; ++m) {
    const int rg = m0 + wr * 64 + m * 16 + (lane >> 4) * 4;
#pragma unroll
    for (int n = 0; n < 4; ++n) {
      const int cg = n0 + wc * 64 + n * 16 + fr;
      const float bb = bias[cg];
#pragma unroll
      for (int j = 0; j < 4; ++j)
        outp[(size_t)(rg + j) * DM + cg] = acc[m][n][j] + bb;
    }
  }
}

// ---------------- flash attention, causal, transposed-MFMA, P-in-register ------
// Q, K: [B,H,T,DH] bf16 (Q pre-scaled by 0.125*log2e).  Vt: [B,H,DH,T] bf16.
// out O: [B,T,DM] bf16.  Block handles q-tiles {NQT-1-pj, pj}: uniform 33 KV tiles.
// S^T = mfma(K,Q): lane (g,fr) holds P[q=fr][kv=c*16+4g+r].  PV uses the SAME kv
// permutation on both P (B-operand) and V (A-operand k-slots), so P feeds PV
// directly from registers: slot(g,e) carries kv = sigma(e) = (e>=4?16:0)+4g+(e&3),
// and V columns are read at {4g..4g+3} and {16+4g..16+4g+3} (ds_read2_b64 pair).
__global__ __launch_bounds__(256) void attn_fwd(const u16* __restrict__ Q,
                                                const u16* __restrict__ K,
                                                const u16* __restrict__ Vt,
                                                u16* __restrict__ O) {
  const int pj = blockIdx.x, h = blockIdx.y, b = blockIdx.z;
  const int tid = threadIdx.x, lane = tid & 63, wave = tid >> 6;
  __shared__ u16 Ks[64 * 72];       // K rows [kv][d], padded stride 72
  __shared__ u16 Vs[64 * 72];       // V^T rows [d][kv], padded stride 72

  const size_t bh = ((size_t)b * HEADS + h) * TT;
  const size_t vbse = ((size_t)b * HEADS + h) * DH;
  const int fr = lane & 15, g = lane >> 4, k8 = g * 8;
  const int sr = tid >> 2, sc = (tid & 3) * 8;

  for (int pass = 0; pass < 2; ++pass) {
    const int qt = pass ? pj : (NQT - 1 - pj);
    const int q0 = qt * 64;
    const int qrow = q0 + wave * 16 + fr;      // this lane's q-row
    const bf16x8 qf0 = *(const bf16x8*)&Q[(bh + qrow) * DH + k8];
    const bf16x8 qf1 = *(const bf16x8*)&Q[(bh + qrow) * DH + 32 + k8];

    float lsum = 0.f;
    f32x4 oacc[4];
#pragma unroll
    for (int c = 0; c < 4; ++c) oacc[c] = (f32x4){0.f, 0.f, 0.f, 0.f};

    // T14: preload tile 0 into registers
    u16x8 ka, kc, va, vc;
    {
      const u16* kg = &K[(bh + sr) * DH + sc];
      ka = *(const u16x8*)kg;
      kc = *(const u16x8*)(kg + 32);
      const u16* vg = &Vt[(vbse + sr) * TT + sc];
      va = *(const u16x8*)vg;
      vc = *(const u16x8*)(vg + 32);
    }

    for (int kvb = 0; kvb <= qt; ++kvb) {
      const int kv0 = kvb * 64;
      __syncthreads();   // all waves done reading previous tile's LDS
      *(u16x8*)&Ks[sr * 72 + sc] = ka;
      *(u16x8*)&Ks[sr * 72 + sc + 32] = kc;
      *(u16x8*)&Vs[sr * 72 + sc] = va;
      *(u16x8*)&Vs[sr * 72 + sc + 32] = vc;
      __syncthreads();   // LDS tile ready

      // T14: issue next tile's global loads; they land during compute
      if (kvb < qt) {
        const u16* kg = &K[(bh + kv0 + 64 + sr) * DH + sc];
        ka = *(const u16x8*)kg;
        kc = *(const u16x8*)(kg + 32);
        const u16* vg = &Vt[(vbse + sr) * TT + kv0 + 64 + sc];
        va = *(const u16x8*)vg;
        vc = *(const u16x8*)(vg + 32);
      }

      // S^T = K Q  (log2 domain; scale folded into Q)
      // lane holds s[c][r] = S[q=qrow][kv = kv0 + c*16 + 4*g + r]
      f32x4 s[4];
      __builtin_amdgcn_s_setprio(1);
#pragma unroll
      for (int c = 0; c < 4; ++c) {
        bf16x8 kb0 = *(const bf16x8*)&Ks[(c * 16 + fr) * 72 + k8];
        bf16x8 kb1 = *(const bf16x8*)&Ks[(c * 16 + fr) * 72 + 32 + k8];
        f32x4 t = (f32x4){0.f, 0.f, 0.f, 0.f};
        t = __builtin_amdgcn_mfma_f32_16x16x32_bf16(kb0, qf0, t, 0, 0, 0);
        t = __builtin_amdgcn_mfma_f32_16x16x32_bf16(kb1, qf1, t, 0, 0, 0);
        s[c] = t;
      }
      __builtin_amdgcn_s_setprio(0);

      if (kvb == qt) {  // diagonal tile: causal mask (in-lane, row = qrow)
#pragma unroll
        for (int c = 0; c < 4; ++c) {
          const int colg = kv0 + c * 16 + 4 * g;
#pragma unroll
          for (int r = 0; r < 4; ++r)
            if (colg + r > qrow) s[c][r] = -1e30f;
        }
      }

      // p = exp2(s), packed in-register; row-sum
      float rs = 0.f;
      uint32_t pk[8];
#pragma unroll
      for (int c = 0; c < 4; ++c) {
        float p0 = __builtin_amdgcn_exp2f(s[c][0]);
        float p1 = __builtin_amdgcn_exp2f(s[c][1]);
        float p2 = __builtin_amdgcn_exp2f(s[c][2]);
        float p3 = __builtin_amdgcn_exp2f(s[c][3]);
        rs += (p0 + p1) + (p2 + p3);
        pk[2 * c] = cvtpk(p0, p1);
        pk[2 * c + 1] = cvtpk(p2, p3);
      }
      rs += __shfl_xor(rs, 16);
      rs += __shfl_xor(rs, 32);
      lsum += rs;

      // pa fragments directly from registers (kv slots: sigma(e)=(e>=4?16:0)+4g+(e&3))
      const bf16x8 pa0 = __builtin_bit_cast(bf16x8, (u32x4){pk[0], pk[1], pk[2], pk[3]});
      const bf16x8 pa1 = __builtin_bit_cast(bf16x8, (u32x4){pk[4], pk[5], pk[6], pk[7]});

      // O^T += V^T P^T  with sigma-permuted kv slots on V
      __builtin_amdgcn_s_setprio(1);
#pragma unroll
      for (int c = 0; c < 4; ++c) {
        const int vrow = (c * 16 + fr) * 72;
        struct V16 { ushort4 a, b; } t0, t1;
        t0.a = *(const ushort4*)&Vs[vrow + 4 * g];
        t0.b = *(const ushort4*)&Vs[vrow + 16 + 4 * g];
        t1.a = *(const ushort4*)&Vs[vrow + 32 + 4 * g];
        t1.b = *(const ushort4*)&Vs[vrow + 48 + 4 * g];
        bf16x8 vb0 = __builtin_bit_cast(bf16x8, t0);
        bf16x8 vb1 = __builtin_bit_cast(bf16x8, t1);
        oacc[c] = __builtin_amdgcn_mfma_f32_16x16x32_bf16(vb0, pa0, oacc[c], 0, 0, 0);
        oacc[c] = __builtin_amdgcn_mfma_f32_16x16x32_bf16(vb1, pa1, oacc[c], 0, 0, 0);
      }
      __builtin_amdgcn_s_setprio(0);
    }

    // epilogue: lane owns O[qrow][d = c*16 + 4g + r] -> packed ushort4 stores
    const float inv = 1.f / lsum;
#pragma unroll
    for (int c = 0; c < 4; ++c) {
      ushort4 o;
      o.x = f2b(oacc[c][0] * inv);
      o.y = f2b(oacc[c][1] * inv);
      o.z = f2b(oacc[c][2] * inv);
      o.w = f2b(oacc[c][3] * inv);
      *(ushort4*)&O[((size_t)b * TT + qrow) * DM + h * DH + c * 16 + 4 * g] = o;
    }
  }
}

extern "C" void kernel_launch(void* const* d_in, const int* in_sizes, int n_in,
                              void* d_out, int out_size, void* d_ws, size_t ws_size,
                              hipStream_t stream) {
  const float* x  = (const float*)d_in[0];
  const float* Wq = (const float*)d_in[1];
  const float* bq = (const float*)d_in[2];
  const float* Wk = (const float*)d_in[3];
  const float* bk = (const float*)d_in[4];
  const float* Wv = (const float*)d_in[5];
  const float* bv = (const float*)d_in[6];
  const float* Wo = (const float*)d_in[7];
  const float* bo = (const float*)d_in[8];

  char* w = (char*)d_ws;
  u16* xb    = (u16*)w; w += (size_t)MTOT * DM * 2;
  u16* Wqkvb = (u16*)w; w += (size_t)3 * DM * DM * 2;
  u16* Wob   = (u16*)w; w += (size_t)DM * DM * 2;
  u16* Qb    = (u16*)w; w += (size_t)MTOT * DM * 2;
  u16* Kb    = (u16*)w; w += (size_t)MTOT * DM * 2;
  u16* Vtb   = (u16*)w; w += (size_t)MTOT * DM * 2;
  u16* AOb   = (u16*)w; w += (size_t)MTOT * DM * 2;

  cast_f32_bf16<<<MTOT * DM / 4 / 256, 256, 0, stream>>>(x, xb, MTOT * DM / 4);
  cast_w3<<<3 * DM * DM / 4 / 256, 256, 0, stream>>>(Wq, Wk, Wv, Wqkvb);
  cast_f32_bf16<<<DM * DM / 4 / 256, 256, 0, stream>>>(Wo, Wob, DM * DM / 4);

  const float qs = 0.125f * 1.44269504f;  // 1/sqrt(64) * log2(e), folded into Q
  gemm_qkv<<<dim3(3 * DM / 128, MTOT / 128), 256, 0, stream>>>(
      xb, Wqkvb, bq, bk, bv, Qb, Kb, Vtb, qs);

  attn_fwd<<<dim3(NQT / 2, HEADS, BQ), 256, 0, stream>>>(Qb, Kb, Vtb, AOb);

  gemm_out<<<dim3(DM / 128, MTOT / 128), 256, 0, stream>>>(AOb, Wob, bo, (float*)d_out);
}

// Round 6
// 196.449 us; speedup vs baseline: 1.1074x; 1.1074x over previous
//
#include <hip/hip_runtime.h>
#include <stdint.h>

#define DM 1024
#define HEADS 16
#define DH 64
#define BQ 4
#define TT 2048
#define MTOT (BQ*TT)  // 8192
#define NQT (TT/64)   // 32 q-tiles per (b,h)

typedef __attribute__((ext_vector_type(8))) __bf16 bf16x8;
typedef __attribute__((ext_vector_type(4))) float f32x4;
typedef __attribute__((ext_vector_type(4))) uint32_t u32x4;
typedef unsigned short u16;
typedef __attribute__((ext_vector_type(8))) unsigned short u16x8;

__device__ __forceinline__ u16 f2b(float f) {
  uint32_t u = __builtin_bit_cast(uint32_t, f);
  u = (u + 0x7fffu + ((u >> 16) & 1u)) >> 16;
  return (u16)u;
}

__device__ __forceinline__ uint32_t cvtpk(float lo, float hi) {
  uint32_t r;
  asm("v_cvt_pk_bf16_f32 %0, %1, %2" : "=v"(r) : "v"(lo), "v"(hi));
  return r;
}

__device__ __forceinline__ void gload_lds16(const u16* g, u16* l) {
  __builtin_amdgcn_global_load_lds(
      (const __attribute__((address_space(1))) void*)g,
      (__attribute__((address_space(3))) void*)l, 16, 0, 0);
}

// ---------------- cast fp32 -> bf16 (vectorized) ----------------
__global__ __launch_bounds__(256) void cast_f32_bf16(const float* __restrict__ in,
                                                     u16* __restrict__ out, int n4) {
  int i = blockIdx.x * 256 + threadIdx.x;
  if (i >= n4) return;
  float4 v = ((const float4*)in)[i];
  ushort4 o;
  o.x = f2b(v.x); o.y = f2b(v.y); o.z = f2b(v.z); o.w = f2b(v.w);
  ((ushort4*)out)[i] = o;
}

// cast three weight matrices into one contiguous [3*DM][DM] bf16 buffer
__global__ __launch_bounds__(256) void cast_w3(const float* __restrict__ W0,
                                               const float* __restrict__ W1,
                                               const float* __restrict__ W2,
                                               u16* __restrict__ out) {
  const int per = DM * DM / 4;  // float4s per matrix
  int i = blockIdx.x * 256 + threadIdx.x;
  const float* src = (i < per) ? W0 : (i < 2 * per) ? W1 : W2;
  int li = (i < per) ? i : (i < 2 * per) ? (i - per) : (i - 2 * per);
  float4 v = ((const float4*)src)[li];
  ushort4 o;
  o.x = f2b(v.x); o.y = f2b(v.y); o.z = f2b(v.z); o.w = f2b(v.w);
  ((ushort4*)out)[i] = o;
}

// ---------------- fused QKV GEMM over N=3072 ----------------
// seg 0 -> Q [B,H,T,DH] scaled; seg 1 -> K [B,H,T,DH];
// seg 2 -> V^T [B,H,DH,T] with sigma-permuted column order within each 64-tile:
//   t -> (t&~63) | block32<<5 | g<<3 | u<<2 | r   where within-64 bits of t are
//   block32=(t>>5)&1, u=(t>>4)&1, g=(t>>2)&3, r=t&3.  This makes attention's PV
//   b128 V-reads deliver exactly the k-slot order of the in-register P operand.
__global__ __launch_bounds__(256) void gemm_qkv(const u16* __restrict__ A,
                                                const u16* __restrict__ Wqkv,
                                                const float* __restrict__ bq,
                                                const float* __restrict__ bk,
                                                const float* __restrict__ bv,
                                                u16* __restrict__ Qo,
                                                u16* __restrict__ Ko,
                                                u16* __restrict__ Vto,
                                                float qs) {
  __shared__ u16 As[128 * 32];
  __shared__ u16 Bs[128 * 32];
  const int tid = threadIdx.x;
  const int lane = tid & 63, wave = tid >> 6;
  const int wr = wave >> 1, wc = wave & 1;
  const int m0 = blockIdx.y * 128, n0 = blockIdx.x * 128;

  f32x4 acc[4][4];
#pragma unroll
  for (int m = 0; m < 4; ++m)
#pragma unroll
    for (int n = 0; n < 4; ++n) acc[m][n] = (f32x4){0.f, 0.f, 0.f, 0.f};

  const int srow = wave * 32 + (lane >> 2);
  const int scol = (lane & 3) * 8;
  const u16* gA = A + (size_t)(m0 + srow) * DM + scol;
  const u16* gB = Wqkv + (size_t)(n0 + srow) * DM + scol;
  u16* lA = &As[wave * 32 * 32];
  u16* lB = &Bs[wave * 32 * 32];
  const int fr = lane & 15;
  const int k8 = (lane >> 4) * 8;

  for (int k0 = 0; k0 < DM; k0 += 32) {
    __syncthreads();
    gload_lds16(gA + k0, lA);
    gload_lds16(gA + k0 + 16 * DM, lA + 16 * 32);
    gload_lds16(gB + k0, lB);
    gload_lds16(gB + k0 + 16 * DM, lB + 16 * 32);
    __syncthreads();
    bf16x8 af[4], bfr[4];
#pragma unroll
    for (int m = 0; m < 4; ++m)
      af[m] = *(const bf16x8*)&As[(wr * 64 + m * 16 + fr) * 32 + k8];
#pragma unroll
    for (int n = 0; n < 4; ++n)
      bfr[n] = *(const bf16x8*)&Bs[(wc * 64 + n * 16 + fr) * 32 + k8];
#pragma unroll
    for (int m = 0; m < 4; ++m)
#pragma unroll
      for (int n = 0; n < 4; ++n)
        acc[m][n] = __builtin_amdgcn_mfma_f32_16x16x32_bf16(af[m], bfr[n], acc[m][n], 0, 0, 0);
  }

#pragma unroll
  for (int m = 0; m < 4; ++m) {
    const int rg = m0 + wr * 64 + m * 16 + (lane >> 4) * 4;
#pragma unroll
    for (int n = 0; n < 4; ++n) {
      const int cg = n0 + wc * 64 + n * 16 + fr;
      const int seg = cg >> 10, cgl = cg & 1023;
      const float bb = (seg == 0 ? bq : seg == 1 ? bk : bv)[cgl];
      const int hh = cgl >> 6, d = cgl & 63;
      const int bi = rg >> 11, t0 = rg & 2047;
      if (seg == 0) {
#pragma unroll
        for (int j = 0; j < 4; ++j)
          Qo[(((size_t)bi * HEADS + hh) * TT + t0 + j) * DH + d] = f2b((acc[m][n][j] + bb) * qs);
      } else if (seg == 1) {
#pragma unroll
        for (int j = 0; j < 4; ++j)
          Ko[(((size_t)bi * HEADS + hh) * TT + t0 + j) * DH + d] = f2b(acc[m][n][j] + bb);
      } else {
        // sigma-permuted position within the 64-tile (t0 % 4 == 0, r spans j)
        const int w64 = t0 & 63;
        const int pos = (t0 & ~63) | (((w64 >> 5) & 1) << 5) | (((w64 >> 2) & 3) << 3) |
                        (((w64 >> 4) & 1) << 2);
        ushort4 o;
        o.x = f2b(acc[m][n][0] + bb);
        o.y = f2b(acc[m][n][1] + bb);
        o.z = f2b(acc[m][n][2] + bb);
        o.w = f2b(acc[m][n][3] + bb);
        *(ushort4*)&Vto[(((size_t)bi * HEADS + hh) * DH + d) * TT + pos] = o;
      }
    }
  }
}

// ---------------- O-projection GEMM: f32 out [M, DM] ----------------
__global__ __launch_bounds__(256) void gemm_out(const u16* __restrict__ A,
                                                const u16* __restrict__ Bw,
                                                const float* __restrict__ bias,
                                                float* __restrict__ outp) {
  __shared__ u16 As[128 * 32];
  __shared__ u16 Bs[128 * 32];
  const int tid = threadIdx.x;
  const int lane = tid & 63, wave = tid >> 6;
  const int wr = wave >> 1, wc = wave & 1;
  const int m0 = blockIdx.y * 128, n0 = blockIdx.x * 128;

  f32x4 acc[4][4];
#pragma unroll
  for (int m = 0; m < 4; ++m)
#pragma unroll
    for (int n = 0; n < 4; ++n) acc[m][n] = (f32x4){0.f, 0.f, 0.f, 0.f};

  const int srow = wave * 32 + (lane >> 2);
  const int scol = (lane & 3) * 8;
  const u16* gA = A + (size_t)(m0 + srow) * DM + scol;
  const u16* gB = Bw + (size_t)(n0 + srow) * DM + scol;
  u16* lA = &As[wave * 32 * 32];
  u16* lB = &Bs[wave * 32 * 32];
  const int fr = lane & 15;
  const int k8 = (lane >> 4) * 8;

  for (int k0 = 0; k0 < DM; k0 += 32) {
    __syncthreads();
    gload_lds16(gA + k0, lA);
    gload_lds16(gA + k0 + 16 * DM, lA + 16 * 32);
    gload_lds16(gB + k0, lB);
    gload_lds16(gB + k0 + 16 * DM, lB + 16 * 32);
    __syncthreads();
    bf16x8 af[4], bfr[4];
#pragma unroll
    for (int m = 0; m < 4; ++m)
      af[m] = *(const bf16x8*)&As[(wr * 64 + m * 16 + fr) * 32 + k8];
#pragma unroll
    for (int n = 0; n < 4; ++n)
      bfr[n] = *(const bf16x8*)&Bs[(wc * 64 + n * 16 + fr) * 32 + k8];
#pragma unroll
    for (int m = 0; m < 4; ++m)
#pragma unroll
      for (int n = 0; n < 4; ++n)
        acc[m][n] = __builtin_amdgcn_mfma_f32_16x16x32_bf16(af[m], bfr[n], acc[m][n], 0, 0, 0);
  }

#pragma unroll
  for (int m = 0; m < 4; ++m) {
    const int rg = m0 + wr * 64 + m * 16 + (lane >> 4) * 4;
#pragma unroll
    for (int n = 0; n < 4; ++n) {
      const int cg = n0 + wc * 64 + n * 16 + fr;
      const float bb = bias[cg];
#pragma unroll
      for (int j = 0; j < 4; ++j)
        outp[(size_t)(rg + j) * DM + cg] = acc[m][n][j] + bb;
    }
  }
}

// ---------------- flash attention, causal, transposed-MFMA, P-in-register ------
// Q, K: [B,H,T,DH] bf16 (Q pre-scaled by 0.125*log2e).
// Vt: [B,H,DH,T] bf16, sigma-permuted within each 64-col tile (see gemm_qkv).
// Round-4 staging structure (proven): stage global->LDS inline, 2 barriers/tile.
// S^T = mfma(K,Q): lane (g,fr) holds P[q=fr][kv=c*16+4g+r]; cvt_pk packs these
// into pa0/pa1 whose k-slot order matches the permuted V columns -> PV reads V
// with the same b128 pattern as K reads, P never touches LDS.
__global__ __launch_bounds__(256) void attn_fwd(const u16* __restrict__ Q,
                                                const u16* __restrict__ K,
                                                const u16* __restrict__ Vt,
                                                u16* __restrict__ O) {
  const int pj = blockIdx.x, h = blockIdx.y, b = blockIdx.z;
  const int tid = threadIdx.x, lane = tid & 63, wave = tid >> 6;
  __shared__ u16 Ks[64 * 72];       // K rows [kv][d], padded stride 72
  __shared__ u16 Vs[64 * 72];       // V^T rows [d][perm-kv], padded stride 72

  const size_t bh = ((size_t)b * HEADS + h) * TT;
  const size_t vbse = ((size_t)b * HEADS + h) * DH;
  const int fr = lane & 15, g = lane >> 4, k8 = g * 8;
  const int sr = tid >> 2, sc = (tid & 3) * 8;

  for (int pass = 0; pass < 2; ++pass) {
    const int qt = pass ? pj : (NQT - 1 - pj);
    const int q0 = qt * 64;
    const int qrow = q0 + wave * 16 + fr;      // this lane's q-row
    const bf16x8 qf0 = *(const bf16x8*)&Q[(bh + qrow) * DH + k8];
    const bf16x8 qf1 = *(const bf16x8*)&Q[(bh + qrow) * DH + 32 + k8];

    float lsum = 0.f;
    f32x4 oacc[4];
#pragma unroll
    for (int c = 0; c < 4; ++c) oacc[c] = (f32x4){0.f, 0.f, 0.f, 0.f};

    for (int kvb = 0; kvb <= qt; ++kvb) {
      const int kv0 = kvb * 64;
      // stage K rows and permuted-V^T rows (round-4 structure)
      {
        const u16* kg = &K[(bh + kv0 + sr) * DH + sc];
        u16x8 ka = *(const u16x8*)kg;
        u16x8 kc = *(const u16x8*)(kg + 32);
        const u16* vg = &Vt[(vbse + sr) * TT + kv0 + sc];
        u16x8 va = *(const u16x8*)vg;
        u16x8 vc = *(const u16x8*)(vg + 32);
        *(u16x8*)&Ks[sr * 72 + sc] = ka;
        *(u16x8*)&Ks[sr * 72 + sc + 32] = kc;
        *(u16x8*)&Vs[sr * 72 + sc] = va;
        *(u16x8*)&Vs[sr * 72 + sc + 32] = vc;
      }
      __syncthreads();

      // S^T = K Q  (log2 domain; scale folded into Q)
      f32x4 s[4];
      __builtin_amdgcn_s_setprio(1);
#pragma unroll
      for (int c = 0; c < 4; ++c) {
        bf16x8 kb0 = *(const bf16x8*)&Ks[(c * 16 + fr) * 72 + k8];
        bf16x8 kb1 = *(const bf16x8*)&Ks[(c * 16 + fr) * 72 + 32 + k8];
        f32x4 t = (f32x4){0.f, 0.f, 0.f, 0.f};
        t = __builtin_amdgcn_mfma_f32_16x16x32_bf16(kb0, qf0, t, 0, 0, 0);
        t = __builtin_amdgcn_mfma_f32_16x16x32_bf16(kb1, qf1, t, 0, 0, 0);
        s[c] = t;
      }
      __builtin_amdgcn_s_setprio(0);

      if (kvb == qt) {  // diagonal tile: causal mask (in-lane, row = qrow)
#pragma unroll
        for (int c = 0; c < 4; ++c) {
          const int colg = kv0 + c * 16 + 4 * g;
#pragma unroll
          for (int r = 0; r < 4; ++r)
            if (colg + r > qrow) s[c][r] = -1e30f;
        }
      }

      // p = exp2(s), packed in-register; row-sum
      float rs = 0.f;
      uint32_t pk[8];
#pragma unroll
      for (int c = 0; c < 4; ++c) {
        float p0 = __builtin_amdgcn_exp2f(s[c][0]);
        float p1 = __builtin_amdgcn_exp2f(s[c][1]);
        float p2 = __builtin_amdgcn_exp2f(s[c][2]);
        float p3 = __builtin_amdgcn_exp2f(s[c][3]);
        rs += (p0 + p1) + (p2 + p3);
        pk[2 * c] = cvtpk(p0, p1);
        pk[2 * c + 1] = cvtpk(p2, p3);
      }
      rs += __shfl_xor(rs, 16);
      rs += __shfl_xor(rs, 32);
      lsum += rs;

      // pa fragments directly from registers; slot order matches permuted V cols
      const bf16x8 pa0 = __builtin_bit_cast(bf16x8, (u32x4){pk[0], pk[1], pk[2], pk[3]});
      const bf16x8 pa1 = __builtin_bit_cast(bf16x8, (u32x4){pk[4], pk[5], pk[6], pk[7]});

      // O^T += V^T P^T   (b128 reads, byte-identical addresses to round 4)
      __builtin_amdgcn_s_setprio(1);
#pragma unroll
      for (int c = 0; c < 4; ++c) {
        bf16x8 vb0 = *(const bf16x8*)&Vs[(c * 16 + fr) * 72 + k8];
        bf16x8 vb1 = *(const bf16x8*)&Vs[(c * 16 + fr) * 72 + 32 + k8];
        oacc[c] = __builtin_amdgcn_mfma_f32_16x16x32_bf16(vb0, pa0, oacc[c], 0, 0, 0);
        oacc[c] = __builtin_amdgcn_mfma_f32_16x16x32_bf16(vb1, pa1, oacc[c], 0, 0, 0);
      }
      __builtin_amdgcn_s_setprio(0);
      __syncthreads();
    }

    // epilogue: lane owns O[qrow][d = c*16 + 4g + r] -> packed ushort4 stores
    const float inv = 1.f / lsum;
#pragma unroll
    for (int c = 0; c < 4; ++c) {
      ushort4 o;
      o.x = f2b(oacc[c][0] * inv);
      o.y = f2b(oacc[c][1] * inv);
      o.z = f2b(oacc[c][2] * inv);
      o.w = f2b(oacc[c][3] * inv);
      *(ushort4*)&O[((size_t)b * TT + qrow) * DM + h * DH + c * 16 + 4 * g] = o;
    }
  }
}

extern "C" void kernel_launch(void* const* d_in, const int* in_sizes, int n_in,
                              void* d_out, int out_size, void* d_ws, size_t ws_size,
                              hipStream_t stream) {
  const float* x  = (const float*)d_in[0];
  const float* Wq = (const float*)d_in[1];
  const float* bq = (const float*)d_in[2];
  const float* Wk = (const float*)d_in[3];
  const float* bk = (const float*)d_in[4];
  const float* Wv = (const float*)d_in[5];
  const float* bv = (const float*)d_in[6];
  const float* Wo = (const float*)d_in[7];
  const float* bo = (const float*)d_in[8];

  char* w = (char*)d_ws;
  u16* xb    = (u16*)w; w += (size_t)MTOT * DM * 2;
  u16* Wqkvb = (u16*)w; w += (size_t)3 * DM * DM * 2;
  u16* Wob   = (u16*)w; w += (size_t)DM * DM * 2;
  u16* Qb    = (u16*)w; w += (size_t)MTOT * DM * 2;
  u16* Kb    = (u16*)w; w += (size_t)MTOT * DM * 2;
  u16* Vtb   = (u16*)w; w += (size_t)MTOT * DM * 2;
  u16* AOb   = (u16*)w; w += (size_t)MTOT * DM * 2;

  cast_f32_bf16<<<MTOT * DM / 4 / 256, 256, 0, stream>>>(x, xb, MTOT * DM / 4);
  cast_w3<<<3 * DM * DM / 4 / 256, 256, 0, stream>>>(Wq, Wk, Wv, Wqkvb);
  cast_f32_bf16<<<DM * DM / 4 / 256, 256, 0, stream>>>(Wo, Wob, DM * DM / 4);

  const float qs = 0.125f * 1.44269504f;  // 1/sqrt(64) * log2(e), folded into Q
  gemm_qkv<<<dim3(3 * DM / 128, MTOT / 128), 256, 0, stream>>>(
      xb, Wqkvb, bq, bk, bv, Qb, Kb, Vtb, qs);

  attn_fwd<<<dim3(NQT / 2, HEADS, BQ), 256, 0, stream>>>(Qb, Kb, Vtb, AOb);

  gemm_out<<<dim3(DM / 128, MTOT / 128), 256, 0, stream>>>(AOb, Wob, bo, (float*)d_out);
}

// Round 7
// 187.199 us; speedup vs baseline: 1.1621x; 1.0494x over previous
//
#include <hip/hip_runtime.h>
#include <stdint.h>

#define DM 1024
#define HEADS 16
#define DH 64
#define BQ 4
#define TT 2048
#define MTOT (BQ*TT)  // 8192
#define NQT (TT/64)   // 32 q-tiles per (b,h)

typedef __attribute__((ext_vector_type(8))) __bf16 bf16x8;
typedef __attribute__((ext_vector_type(4))) float f32x4;
typedef __attribute__((ext_vector_type(4))) uint32_t u32x4;
typedef unsigned short u16;
typedef __attribute__((ext_vector_type(8))) unsigned short u16x8;

__device__ __forceinline__ u16 f2b(float f) {
  uint32_t u = __builtin_bit_cast(uint32_t, f);
  u = (u + 0x7fffu + ((u >> 16) & 1u)) >> 16;
  return (u16)u;
}

__device__ __forceinline__ uint32_t cvtpk(float lo, float hi) {
  uint32_t r;
  asm("v_cvt_pk_bf16_f32 %0, %1, %2" : "=v"(r) : "v"(lo), "v"(hi));
  return r;
}

__device__ __forceinline__ void gload_lds16(const u16* g, u16* l) {
  __builtin_amdgcn_global_load_lds(
      (const __attribute__((address_space(1))) void*)g,
      (__attribute__((address_space(3))) void*)l, 16, 0, 0);
}

// ---------------- cast fp32 -> bf16 (vectorized) ----------------
__global__ __launch_bounds__(256) void cast_f32_bf16(const float* __restrict__ in,
                                                     u16* __restrict__ out, int n4) {
  int i = blockIdx.x * 256 + threadIdx.x;
  if (i >= n4) return;
  float4 v = ((const float4*)in)[i];
  ushort4 o;
  o.x = f2b(v.x); o.y = f2b(v.y); o.z = f2b(v.z); o.w = f2b(v.w);
  ((ushort4*)out)[i] = o;
}

// cast three weight matrices into one contiguous [3*DM][DM] bf16 buffer
__global__ __launch_bounds__(256) void cast_w3(const float* __restrict__ W0,
                                               const float* __restrict__ W1,
                                               const float* __restrict__ W2,
                                               u16* __restrict__ out) {
  const int per = DM * DM / 4;  // float4s per matrix
  int i = blockIdx.x * 256 + threadIdx.x;
  const float* src = (i < per) ? W0 : (i < 2 * per) ? W1 : W2;
  int li = (i < per) ? i : (i < 2 * per) ? (i - per) : (i - 2 * per);
  float4 v = ((const float4*)src)[li];
  ushort4 o;
  o.x = f2b(v.x); o.y = f2b(v.y); o.z = f2b(v.z); o.w = f2b(v.w);
  ((ushort4*)out)[i] = o;
}

// ---------------- fused QKV GEMM, 256x256 tile, counted-vmcnt pipeline --------
// A: [MTOT][DM] bf16.  W: [3*DM][DM] bf16 (rows = output cols; B^T GEMM).
// 4-slot LDS ring (BK=32, 32KB/slot, 128KB total), depth-3 prefetch, vmcnt(8)
// steady state (never drained in main loop).  8 waves = 2(M) x 4(N); per-wave
// C = 128x64 = 8mi x 4ni fragments.  LDS 16B-chunk swizzle: chunk ^= (row>>1)&3
// applied on BOTH sides (pre-swizzled global source for global_load_lds's
// linear write; XOR on ds_read address).
// Epilogue: seg 0 -> Q [B,H,T,DH] scaled by qs; seg 1 -> K [B,H,T,DH];
// seg 2 -> V^T [B,H,DH,T] sigma-permuted within each 64-col tile (round-6
// contract with attn_fwd, unchanged).
#define BKq 32
#define NKq (DM / BKq)          // 32 K-tiles
#define SLOT_A (256 * BKq)      // 8192 elems (16KB)
#define SLOT_E (2 * SLOT_A)     // 16384 elems (32KB) per slot

__global__ __launch_bounds__(512, 2) void gemm_qkv8(const u16* __restrict__ A,
                                                    const u16* __restrict__ W,
                                                    const float* __restrict__ bq,
                                                    const float* __restrict__ bk,
                                                    const float* __restrict__ bv,
                                                    u16* __restrict__ Qo,
                                                    u16* __restrict__ Ko,
                                                    u16* __restrict__ Vto,
                                                    float qs) {
  __shared__ u16 lds[4 * SLOT_E];  // 128 KB
  const int tid = threadIdx.x, lane = tid & 63, wave = tid >> 6;
  const int fr = lane & 15, g = lane >> 4;
  const int wm = wave >> 2, wn = wave & 3;

  // T1: bijective XCD swizzle (384 blocks, 384 % 8 == 0)
  int bid = blockIdx.x;
  bid = (bid & 7) * 48 + (bid >> 3);
  const int bx = bid % 12, by = bid / 12;     // bx: n-tile, by: m-tile
  const int m0 = by * 256, n0 = bx * 256;

  // ---- staging addresses (per-thread global, pre-swizzled chunk) ----
  const int srow = tid >> 2;                               // 0..127
  const int schunk = (tid & 3) ^ ((tid >> 3) & 3);         // swizzled 16B chunk
  const u16* gA0 = A + (size_t)(m0 + srow) * DM + schunk * 8;
  const u16* gA1 = gA0 + (size_t)128 * DM;
  const u16* gB0 = W + (size_t)(n0 + srow) * DM + schunk * 8;
  const u16* gB1 = gB0 + (size_t)128 * DM;
  // wave-uniform LDS dests (elements): wave covers rows wave*16..+15 per inst
  const int dA0 = wave * 512;            // (wave*16 rows)*32
  const int dA1 = 4096 + wave * 512;     // +128 rows
  const int dB0 = SLOT_A + wave * 512;
  const int dB1 = SLOT_A + 4096 + wave * 512;

#define STAGEQ(slot, kt) {                                   \
    u16* ls = &lds[(slot) * SLOT_E];                         \
    const int ke = (kt) * BKq;                               \
    gload_lds16(gA0 + ke, ls + dA0);                         \
    gload_lds16(gA1 + ke, ls + dA1);                         \
    gload_lds16(gB0 + ke, ls + dB0);                         \
    gload_lds16(gB1 + ke, ls + dB1); }

  // ---- fragment read offsets (lane-dependent, swizzled chunk) ----
  const int rchunk = (g ^ ((fr >> 1) & 3)) * 8;
  const int offA = (wm * 128 + fr) * 32 + rchunk;           // + mi*512
  const int offB = SLOT_A + (wn * 64 + fr) * 32 + rchunk;   // + ni*512

  f32x4 acc[8][4];
#pragma unroll
  for (int mi = 0; mi < 8; ++mi)
#pragma unroll
    for (int ni = 0; ni < 4; ++ni) acc[mi][ni] = (f32x4){0.f, 0.f, 0.f, 0.f};

  auto compute = [&](int kt) {
    const u16* sl = &lds[(kt & 3) * SLOT_E];
    bf16x8 af[8], bf[4];
#pragma unroll
    for (int mi = 0; mi < 8; ++mi) af[mi] = *(const bf16x8*)&sl[offA + mi * 512];
#pragma unroll
    for (int ni = 0; ni < 4; ++ni) bf[ni] = *(const bf16x8*)&sl[offB + ni * 512];
    __builtin_amdgcn_s_setprio(1);
#pragma unroll
    for (int mi = 0; mi < 8; ++mi)
#pragma unroll
      for (int ni = 0; ni < 4; ++ni)
        acc[mi][ni] = __builtin_amdgcn_mfma_f32_16x16x32_bf16(af[mi], bf[ni], acc[mi][ni], 0, 0, 0);
    __builtin_amdgcn_s_setprio(0);
  };

  // ---- prologue: stage kt = 0,1,2; wait slot0 ----
  STAGEQ(0, 0)
  STAGEQ(1, 1)
  STAGEQ(2, 2)
  asm volatile("s_waitcnt vmcnt(8)" ::: "memory");
  asm volatile("s_barrier" ::: "memory");

  // ---- main loop: stage kt+3, keep 8 loads in flight ----
  for (int kt = 0; kt < NKq - 3; ++kt) {
    STAGEQ((kt + 3) & 3, kt + 3)
    compute(kt);
    asm volatile("s_waitcnt vmcnt(8)" ::: "memory");
    asm volatile("s_barrier" ::: "memory");
  }
  // ---- epilogue phases: drain 8 -> 4 -> 0 ----
  compute(NKq - 3);
  asm volatile("s_waitcnt vmcnt(4)" ::: "memory");
  asm volatile("s_barrier" ::: "memory");
  compute(NKq - 2);
  asm volatile("s_waitcnt vmcnt(0)" ::: "memory");
  asm volatile("s_barrier" ::: "memory");
  compute(NKq - 1);

  // ---- epilogue: m = m0 + wm*128 + mi*16 + g*4 + j ; n = n0 + wn*64 + ni*16 + fr
  const int g4 = g * 4;
  const int seg = n0 >> 10;
  const int nbase = (n0 & 1023) + wn * 64 + fr;
  if (seg == 0) {
#pragma unroll
    for (int ni = 0; ni < 4; ++ni) {
      const int cgl = nbase + ni * 16;
      const float bb = bq[cgl];
      const int hh = cgl >> 6, d = cgl & 63;
#pragma unroll
      for (int mi = 0; mi < 8; ++mi) {
        const int m = m0 + wm * 128 + mi * 16 + g4;
        const int bi = m >> 11, t = m & 2047;
        u16* dst = &Qo[(((size_t)bi * HEADS + hh) * TT + t) * DH + d];
#pragma unroll
        for (int j = 0; j < 4; ++j)
          dst[(size_t)j * DH] = f2b((acc[mi][ni][j] + bb) * qs);
      }
    }
  } else if (seg == 1) {
#pragma unroll
    for (int ni = 0; ni < 4; ++ni) {
      const int cgl = nbase + ni * 16;
      const float bb = bk[cgl];
      const int hh = cgl >> 6, d = cgl & 63;
#pragma unroll
      for (int mi = 0; mi < 8; ++mi) {
        const int m = m0 + wm * 128 + mi * 16 + g4;
        const int bi = m >> 11, t = m & 2047;
        u16* dst = &Ko[(((size_t)bi * HEADS + hh) * TT + t) * DH + d];
#pragma unroll
        for (int j = 0; j < 4; ++j)
          dst[(size_t)j * DH] = f2b(acc[mi][ni][j] + bb);
      }
    }
  } else {
#pragma unroll
    for (int ni = 0; ni < 4; ++ni) {
      const int cgl = nbase + ni * 16;
      const float bb = bv[cgl];
      const int hh = cgl >> 6, d = cgl & 63;
#pragma unroll
      for (int mi = 0; mi < 8; ++mi) {
        const int t0 = (m0 + wm * 128 + mi * 16 + g4) & 2047;
        const int bi = (m0 + wm * 128 + mi * 16 + g4) >> 11;
        const int w64 = t0 & 63;
        const int pos = (t0 & ~63) | (((w64 >> 5) & 1) << 5) | (((w64 >> 2) & 3) << 3) |
                        (((w64 >> 4) & 1) << 2);
        ushort4 o;
        o.x = f2b(acc[mi][ni][0] + bb);
        o.y = f2b(acc[mi][ni][1] + bb);
        o.z = f2b(acc[mi][ni][2] + bb);
        o.w = f2b(acc[mi][ni][3] + bb);
        *(ushort4*)&Vto[(((size_t)bi * HEADS + hh) * DH + d) * TT + pos] = o;
      }
    }
  }
#undef STAGEQ
}

// ---------------- O-projection GEMM: f32 out [M, DM] ----------------
__global__ __launch_bounds__(256) void gemm_out(const u16* __restrict__ A,
                                                const u16* __restrict__ Bw,
                                                const float* __restrict__ bias,
                                                float* __restrict__ outp) {
  __shared__ u16 As[128 * 32];
  __shared__ u16 Bs[128 * 32];
  const int tid = threadIdx.x;
  const int lane = tid & 63, wave = tid >> 6;
  const int wr = wave >> 1, wc = wave & 1;
  const int m0 = blockIdx.y * 128, n0 = blockIdx.x * 128;

  f32x4 acc[4][4];
#pragma unroll
  for (int m = 0; m < 4; ++m)
#pragma unroll
    for (int n = 0; n < 4; ++n) acc[m][n] = (f32x4){0.f, 0.f, 0.f, 0.f};

  const int srow = wave * 32 + (lane >> 2);
  const int scol = (lane & 3) * 8;
  const u16* gA = A + (size_t)(m0 + srow) * DM + scol;
  const u16* gB = Bw + (size_t)(n0 + srow) * DM + scol;
  u16* lA = &As[wave * 32 * 32];
  u16* lB = &Bs[wave * 32 * 32];
  const int fr = lane & 15;
  const int k8 = (lane >> 4) * 8;

  for (int k0 = 0; k0 < DM; k0 += 32) {
    __syncthreads();
    gload_lds16(gA + k0, lA);
    gload_lds16(gA + k0 + 16 * DM, lA + 16 * 32);
    gload_lds16(gB + k0, lB);
    gload_lds16(gB + k0 + 16 * DM, lB + 16 * 32);
    __syncthreads();
    bf16x8 af[4], bfr[4];
#pragma unroll
    for (int m = 0; m < 4; ++m)
      af[m] = *(const bf16x8*)&As[(wr * 64 + m * 16 + fr) * 32 + k8];
#pragma unroll
    for (int n = 0; n < 4; ++n)
      bfr[n] = *(const bf16x8*)&Bs[(wc * 64 + n * 16 + fr) * 32 + k8];
#pragma unroll
    for (int m = 0; m < 4; ++m)
#pragma unroll
      for (int n = 0; n < 4; ++n)
        acc[m][n] = __builtin_amdgcn_mfma_f32_16x16x32_bf16(af[m], bfr[n], acc[m][n], 0, 0, 0);
  }

#pragma unroll
  for (int m = 0; m < 4; ++m) {
    const int rg = m0 + wr * 64 + m * 16 + (lane >> 4) * 4;
#pragma unroll
    for (int n = 0; n < 4; ++n) {
      const int cg = n0 + wc * 64 + n * 16 + fr;
      const float bb = bias[cg];
#pragma unroll
      for (int j = 0; j < 4; ++j)
        outp[(size_t)(rg + j) * DM + cg] = acc[m][n][j] + bb;
    }
  }
}

// ---------------- flash attention, causal, transposed-MFMA, P-in-register ------
// (unchanged from round 6)
__global__ __launch_bounds__(256) void attn_fwd(const u16* __restrict__ Q,
                                                const u16* __restrict__ K,
                                                const u16* __restrict__ Vt,
                                                u16* __restrict__ O) {
  const int pj = blockIdx.x, h = blockIdx.y, b = blockIdx.z;
  const int tid = threadIdx.x, lane = tid & 63, wave = tid >> 6;
  __shared__ u16 Ks[64 * 72];       // K rows [kv][d], padded stride 72
  __shared__ u16 Vs[64 * 72];       // V^T rows [d][perm-kv], padded stride 72

  const size_t bh = ((size_t)b * HEADS + h) * TT;
  const size_t vbse = ((size_t)b * HEADS + h) * DH;
  const int fr = lane & 15, g = lane >> 4, k8 = g * 8;
  const int sr = tid >> 2, sc = (tid & 3) * 8;

  for (int pass = 0; pass < 2; ++pass) {
    const int qt = pass ? pj : (NQT - 1 - pj);
    const int q0 = qt * 64;
    const int qrow = q0 + wave * 16 + fr;      // this lane's q-row
    const bf16x8 qf0 = *(const bf16x8*)&Q[(bh + qrow) * DH + k8];
    const bf16x8 qf1 = *(const bf16x8*)&Q[(bh + qrow) * DH + 32 + k8];

    float lsum = 0.f;
    f32x4 oacc[4];
#pragma unroll
    for (int c = 0; c < 4; ++c) oacc[c] = (f32x4){0.f, 0.f, 0.f, 0.f};

    for (int kvb = 0; kvb <= qt; ++kvb) {
      const int kv0 = kvb * 64;
      {
        const u16* kg = &K[(bh + kv0 + sr) * DH + sc];
        u16x8 ka = *(const u16x8*)kg;
        u16x8 kc = *(const u16x8*)(kg + 32);
        const u16* vg = &Vt[(vbse + sr) * TT + kv0 + sc];
        u16x8 va = *(const u16x8*)vg;
        u16x8 vc = *(const u16x8*)(vg + 32);
        *(u16x8*)&Ks[sr * 72 + sc] = ka;
        *(u16x8*)&Ks[sr * 72 + sc + 32] = kc;
        *(u16x8*)&Vs[sr * 72 + sc] = va;
        *(u16x8*)&Vs[sr * 72 + sc + 32] = vc;
      }
      __syncthreads();

      // S^T = K Q  (log2 domain; scale folded into Q)
      f32x4 s[4];
      __builtin_amdgcn_s_setprio(1);
#pragma unroll
      for (int c = 0; c < 4; ++c) {
        bf16x8 kb0 = *(const bf16x8*)&Ks[(c * 16 + fr) * 72 + k8];
        bf16x8 kb1 = *(const bf16x8*)&Ks[(c * 16 + fr) * 72 + 32 + k8];
        f32x4 t = (f32x4){0.f, 0.f, 0.f, 0.f};
        t = __builtin_amdgcn_mfma_f32_16x16x32_bf16(kb0, qf0, t, 0, 0, 0);
        t = __builtin_amdgcn_mfma_f32_16x16x32_bf16(kb1, qf1, t, 0, 0, 0);
        s[c] = t;
      }
      __builtin_amdgcn_s_setprio(0);

      if (kvb == qt) {  // diagonal tile: causal mask (in-lane, row = qrow)
#pragma unroll
        for (int c = 0; c < 4; ++c) {
          const int colg = kv0 + c * 16 + 4 * g;
#pragma unroll
          for (int r = 0; r < 4; ++r)
            if (colg + r > qrow) s[c][r] = -1e30f;
        }
      }

      // p = exp2(s), packed in-register; row-sum
      float rs = 0.f;
      uint32_t pk[8];
#pragma unroll
      for (int c = 0; c < 4; ++c) {
        float p0 = __builtin_amdgcn_exp2f(s[c][0]);
        float p1 = __builtin_amdgcn_exp2f(s[c][1]);
        float p2 = __builtin_amdgcn_exp2f(s[c][2]);
        float p3 = __builtin_amdgcn_exp2f(s[c][3]);
        rs += (p0 + p1) + (p2 + p3);
        pk[2 * c] = cvtpk(p0, p1);
        pk[2 * c + 1] = cvtpk(p2, p3);
      }
      rs += __shfl_xor(rs, 16);
      rs += __shfl_xor(rs, 32);
      lsum += rs;

      const bf16x8 pa0 = __builtin_bit_cast(bf16x8, (u32x4){pk[0], pk[1], pk[2], pk[3]});
      const bf16x8 pa1 = __builtin_bit_cast(bf16x8, (u32x4){pk[4], pk[5], pk[6], pk[7]});

      // O^T += V^T P^T   (b128 reads; V columns pre-permuted to match pa slots)
      __builtin_amdgcn_s_setprio(1);
#pragma unroll
      for (int c = 0; c < 4; ++c) {
        bf16x8 vb0 = *(const bf16x8*)&Vs[(c * 16 + fr) * 72 + k8];
        bf16x8 vb1 = *(const bf16x8*)&Vs[(c * 16 + fr) * 72 + 32 + k8];
        oacc[c] = __builtin_amdgcn_mfma_f32_16x16x32_bf16(vb0, pa0, oacc[c], 0, 0, 0);
        oacc[c] = __builtin_amdgcn_mfma_f32_16x16x32_bf16(vb1, pa1, oacc[c], 0, 0, 0);
      }
      __builtin_amdgcn_s_setprio(0);
      __syncthreads();
    }

    // epilogue: lane owns O[qrow][d = c*16 + 4g + r] -> packed ushort4 stores
    const float inv = 1.f / lsum;
#pragma unroll
    for (int c = 0; c < 4; ++c) {
      ushort4 o;
      o.x = f2b(oacc[c][0] * inv);
      o.y = f2b(oacc[c][1] * inv);
      o.z = f2b(oacc[c][2] * inv);
      o.w = f2b(oacc[c][3] * inv);
      *(ushort4*)&O[((size_t)b * TT + qrow) * DM + h * DH + c * 16 + 4 * g] = o;
    }
  }
}

extern "C" void kernel_launch(void* const* d_in, const int* in_sizes, int n_in,
                              void* d_out, int out_size, void* d_ws, size_t ws_size,
                              hipStream_t stream) {
  const float* x  = (const float*)d_in[0];
  const float* Wq = (const float*)d_in[1];
  const float* bq = (const float*)d_in[2];
  const float* Wk = (const float*)d_in[3];
  const float* bk = (const float*)d_in[4];
  const float* Wv = (const float*)d_in[5];
  const float* bv = (const float*)d_in[6];
  const float* Wo = (const float*)d_in[7];
  const float* bo = (const float*)d_in[8];

  char* w = (char*)d_ws;
  u16* xb    = (u16*)w; w += (size_t)MTOT * DM * 2;
  u16* Wqkvb = (u16*)w; w += (size_t)3 * DM * DM * 2;
  u16* Wob   = (u16*)w; w += (size_t)DM * DM * 2;
  u16* Qb    = (u16*)w; w += (size_t)MTOT * DM * 2;
  u16* Kb    = (u16*)w; w += (size_t)MTOT * DM * 2;
  u16* Vtb   = (u16*)w; w += (size_t)MTOT * DM * 2;
  u16* AOb   = (u16*)w; w += (size_t)MTOT * DM * 2;

  cast_f32_bf16<<<MTOT * DM / 4 / 256, 256, 0, stream>>>(x, xb, MTOT * DM / 4);
  cast_w3<<<3 * DM * DM / 4 / 256, 256, 0, stream>>>(Wq, Wk, Wv, Wqkvb);
  cast_f32_bf16<<<DM * DM / 4 / 256, 256, 0, stream>>>(Wo, Wob, DM * DM / 4);

  const float qs = 0.125f * 1.44269504f;  // 1/sqrt(64) * log2(e), folded into Q
  gemm_qkv8<<<384, 512, 0, stream>>>(xb, Wqkvb, bq, bk, bv, Qb, Kb, Vtb, qs);

  attn_fwd<<<dim3(NQT / 2, HEADS, BQ), 256, 0, stream>>>(Qb, Kb, Vtb, AOb);

  gemm_out<<<dim3(DM / 128, MTOT / 128), 256, 0, stream>>>(AOb, Wob, bo, (float*)d_out);
}

// Round 8
// 184.727 us; speedup vs baseline: 1.1777x; 1.0134x over previous
//
#include <hip/hip_runtime.h>
#include <stdint.h>

#define DM 1024
#define HEADS 16
#define DH 64
#define BQ 4
#define TT 2048
#define MTOT (BQ*TT)  // 8192
#define NQT (TT/64)   // 32 q-tiles per (b,h)

typedef __attribute__((ext_vector_type(8))) __bf16 bf16x8;
typedef __attribute__((ext_vector_type(4))) float f32x4;
typedef __attribute__((ext_vector_type(4))) uint32_t u32x4;
typedef unsigned short u16;
typedef __attribute__((ext_vector_type(8))) unsigned short u16x8;

__device__ __forceinline__ u16 f2b(float f) {
  uint32_t u = __builtin_bit_cast(uint32_t, f);
  u = (u + 0x7fffu + ((u >> 16) & 1u)) >> 16;
  return (u16)u;
}

__device__ __forceinline__ uint32_t cvtpk(float lo, float hi) {
  uint32_t r;
  asm("v_cvt_pk_bf16_f32 %0, %1, %2" : "=v"(r) : "v"(lo), "v"(hi));
  return r;
}

__device__ __forceinline__ void gload_lds16(const u16* g, u16* l) {
  __builtin_amdgcn_global_load_lds(
      (const __attribute__((address_space(1))) void*)g,
      (__attribute__((address_space(3))) void*)l, 16, 0, 0);
}

// ---------------- cast fp32 -> bf16 (vectorized) ----------------
__global__ __launch_bounds__(256) void cast_f32_bf16(const float* __restrict__ in,
                                                     u16* __restrict__ out, int n4) {
  int i = blockIdx.x * 256 + threadIdx.x;
  if (i >= n4) return;
  float4 v = ((const float4*)in)[i];
  ushort4 o;
  o.x = f2b(v.x); o.y = f2b(v.y); o.z = f2b(v.z); o.w = f2b(v.w);
  ((ushort4*)out)[i] = o;
}

// cast three weight matrices into one contiguous [3*DM][DM] bf16 buffer
__global__ __launch_bounds__(256) void cast_w3(const float* __restrict__ W0,
                                               const float* __restrict__ W1,
                                               const float* __restrict__ W2,
                                               u16* __restrict__ out) {
  const int per = DM * DM / 4;  // float4s per matrix
  int i = blockIdx.x * 256 + threadIdx.x;
  const float* src = (i < per) ? W0 : (i < 2 * per) ? W1 : W2;
  int li = (i < per) ? i : (i < 2 * per) ? (i - per) : (i - 2 * per);
  float4 v = ((const float4*)src)[li];
  ushort4 o;
  o.x = f2b(v.x); o.y = f2b(v.y); o.z = f2b(v.z); o.w = f2b(v.w);
  ((ushort4*)out)[i] = o;
}

// ---------------- fused QKV GEMM, 256x256 tile, counted-vmcnt + reg dbuf ------
// 4-slot LDS ring (BK=32, 32KB/slot), tail-staged depth-2 in flight, vmcnt(4)
// steady state.  Per step: [vmcnt(4); barrier; ds_read frags(kt+1)->bufNext;
// MFMA(kt, bufCur); STAGE(kt+3)].  Compiler emits counted lgkmcnt(12) before
// the MFMA cluster, so bufNext's reads overlap the MFMAs.  Race-free: slot
// kt-1's reads are lgkm-retired before barrier(kt); STAGE(kt+3)->slot(kt-1)
// issues only after barrier(kt).
#define BKq 32
#define NKq (DM / BKq)          // 32 K-tiles
#define SLOT_A (256 * BKq)      // 8192 elems (16KB)
#define SLOT_E (2 * SLOT_A)     // 16384 elems (32KB) per slot

__global__ __launch_bounds__(512, 2) void gemm_qkv8(const u16* __restrict__ A,
                                                    const u16* __restrict__ W,
                                                    const float* __restrict__ bq,
                                                    const float* __restrict__ bk,
                                                    const float* __restrict__ bv,
                                                    u16* __restrict__ Qo,
                                                    u16* __restrict__ Ko,
                                                    u16* __restrict__ Vto,
                                                    float qs) {
  __shared__ u16 lds[4 * SLOT_E];  // 128 KB
  const int tid = threadIdx.x, lane = tid & 63, wave = tid >> 6;
  const int fr = lane & 15, g = lane >> 4;
  const int wm = wave >> 2, wn = wave & 3;

  // T1: bijective XCD swizzle (384 blocks, 384 % 8 == 0)
  int bid = blockIdx.x;
  bid = (bid & 7) * 48 + (bid >> 3);
  const int bx = bid % 12, by = bid / 12;     // bx: n-tile, by: m-tile
  const int m0 = by * 256, n0 = bx * 256;

  // ---- staging addresses (per-thread global, pre-swizzled chunk) ----
  const int srow = tid >> 2;                               // 0..127
  const int schunk = (tid & 3) ^ ((tid >> 3) & 3);         // swizzled 16B chunk
  const u16* gA0 = A + (size_t)(m0 + srow) * DM + schunk * 8;
  const u16* gA1 = gA0 + (size_t)128 * DM;
  const u16* gB0 = W + (size_t)(n0 + srow) * DM + schunk * 8;
  const u16* gB1 = gB0 + (size_t)128 * DM;
  const int dA0 = wave * 512;
  const int dA1 = 4096 + wave * 512;
  const int dB0 = SLOT_A + wave * 512;
  const int dB1 = SLOT_A + 4096 + wave * 512;

#define STAGEQ(slot, kt) {                                   \
    u16* ls = &lds[(slot) * SLOT_E];                         \
    const int ke = (kt) * BKq;                               \
    gload_lds16(gA0 + ke, ls + dA0);                         \
    gload_lds16(gA1 + ke, ls + dA1);                         \
    gload_lds16(gB0 + ke, ls + dB0);                         \
    gload_lds16(gB1 + ke, ls + dB1); }

  // ---- fragment read offsets (lane-dependent, swizzled chunk) ----
  const int rchunk = (g ^ ((fr >> 1) & 3)) * 8;
  const int offA = (wm * 128 + fr) * 32 + rchunk;           // + mi*512
  const int offB = SLOT_A + (wn * 64 + fr) * 32 + rchunk;   // + ni*512

  f32x4 acc[8][4];
#pragma unroll
  for (int mi = 0; mi < 8; ++mi)
#pragma unroll
    for (int ni = 0; ni < 4; ++ni) acc[mi][ni] = (f32x4){0.f, 0.f, 0.f, 0.f};

  bf16x8 afA[8], bfA[4], afB[8], bfB[4];

#define READQ(AFv, BFv, kt) {                                \
    const u16* sl = &lds[((kt) & 3) * SLOT_E];               \
    _Pragma("unroll")                                        \
    for (int mi = 0; mi < 8; ++mi)                           \
      AFv[mi] = *(const bf16x8*)&sl[offA + mi * 512];        \
    _Pragma("unroll")                                        \
    for (int ni = 0; ni < 4; ++ni)                           \
      BFv[ni] = *(const bf16x8*)&sl[offB + ni * 512]; }

#define MFMAQ(AFv, BFv) {                                    \
    __builtin_amdgcn_s_setprio(1);                           \
    _Pragma("unroll")                                        \
    for (int mi = 0; mi < 8; ++mi)                           \
      _Pragma("unroll")                                      \
      for (int ni = 0; ni < 4; ++ni)                         \
        acc[mi][ni] = __builtin_amdgcn_mfma_f32_16x16x32_bf16(AFv[mi], BFv[ni], acc[mi][ni], 0, 0, 0); \
    __builtin_amdgcn_s_setprio(0); }

#define WAIT4 asm volatile("s_waitcnt vmcnt(4)" ::: "memory"); \
              asm volatile("s_barrier" ::: "memory");
#define WAIT0 asm volatile("s_waitcnt vmcnt(0)" ::: "memory"); \
              asm volatile("s_barrier" ::: "memory");

  // ---- prologue: stage 0,1,2; wait stage0; read frags(0) ----
  STAGEQ(0, 0)
  STAGEQ(1, 1)
  STAGEQ(2, 2)
  asm volatile("s_waitcnt vmcnt(8)" ::: "memory");
  asm volatile("s_barrier" ::: "memory");
  READQ(afA, bfA, 0)

  // ---- main loop (pairs; bufA even steps, bufB odd) kt = 0..27 ----
  for (int kt = 0; kt < NKq - 4; kt += 2) {
    WAIT4                      // retires stage(kt+1)
    READQ(afB, bfB, kt + 1)
    MFMAQ(afA, bfA)
    STAGEQ((kt + 3) & 3, kt + 3)
    WAIT4                      // retires stage(kt+2)
    READQ(afA, bfA, kt + 2)
    MFMAQ(afB, bfB)
    STAGEQ((kt + 4) & 3, kt + 4)
  }
  // ---- peeled steps 28..31 ----
  WAIT4                        // retires stage 29
  READQ(afB, bfB, NKq - 3)
  MFMAQ(afA, bfA)              // kt = 28
  STAGEQ((NKq - 1) & 3, NKq - 1)
  WAIT4                        // retires stage 30
  READQ(afA, bfA, NKq - 2)
  MFMAQ(afB, bfB)              // kt = 29
  WAIT0                        // retires stage 31
  READQ(afB, bfB, NKq - 1)
  MFMAQ(afA, bfA)              // kt = 30
  MFMAQ(afB, bfB)              // kt = 31

  // ---- epilogue: m = m0 + wm*128 + mi*16 + g*4 + j ; n = n0 + wn*64 + ni*16 + fr
  const int g4 = g * 4;
  const int seg = n0 >> 10;
  const int nbase = (n0 & 1023) + wn * 64 + fr;
  if (seg == 0) {
#pragma unroll
    for (int ni = 0; ni < 4; ++ni) {
      const int cgl = nbase + ni * 16;
      const float bb = bq[cgl];
      const int hh = cgl >> 6, d = cgl & 63;
#pragma unroll
      for (int mi = 0; mi < 8; ++mi) {
        const int m = m0 + wm * 128 + mi * 16 + g4;
        const int bi = m >> 11, t = m & 2047;
        u16* dst = &Qo[(((size_t)bi * HEADS + hh) * TT + t) * DH + d];
#pragma unroll
        for (int j = 0; j < 4; ++j)
          dst[(size_t)j * DH] = f2b((acc[mi][ni][j] + bb) * qs);
      }
    }
  } else if (seg == 1) {
#pragma unroll
    for (int ni = 0; ni < 4; ++ni) {
      const int cgl = nbase + ni * 16;
      const float bb = bk[cgl];
      const int hh = cgl >> 6, d = cgl & 63;
#pragma unroll
      for (int mi = 0; mi < 8; ++mi) {
        const int m = m0 + wm * 128 + mi * 16 + g4;
        const int bi = m >> 11, t = m & 2047;
        u16* dst = &Ko[(((size_t)bi * HEADS + hh) * TT + t) * DH + d];
#pragma unroll
        for (int j = 0; j < 4; ++j)
          dst[(size_t)j * DH] = f2b(acc[mi][ni][j] + bb);
      }
    }
  } else {
#pragma unroll
    for (int ni = 0; ni < 4; ++ni) {
      const int cgl = nbase + ni * 16;
      const float bb = bv[cgl];
      const int hh = cgl >> 6, d = cgl & 63;
#pragma unroll
      for (int mi = 0; mi < 8; ++mi) {
        const int t0 = (m0 + wm * 128 + mi * 16 + g4) & 2047;
        const int bi = (m0 + wm * 128 + mi * 16 + g4) >> 11;
        const int w64 = t0 & 63;
        const int pos = (t0 & ~63) | (((w64 >> 5) & 1) << 5) | (((w64 >> 2) & 3) << 3) |
                        (((w64 >> 4) & 1) << 2);
        ushort4 o;
        o.x = f2b(acc[mi][ni][0] + bb);
        o.y = f2b(acc[mi][ni][1] + bb);
        o.z = f2b(acc[mi][ni][2] + bb);
        o.w = f2b(acc[mi][ni][3] + bb);
        *(ushort4*)&Vto[(((size_t)bi * HEADS + hh) * DH + d) * TT + pos] = o;
      }
    }
  }
#undef STAGEQ
#undef READQ
#undef MFMAQ
#undef WAIT4
#undef WAIT0
}

// ---------------- O-projection GEMM: f32 out [M, DM] ----------------
__global__ __launch_bounds__(256) void gemm_out(const u16* __restrict__ A,
                                                const u16* __restrict__ Bw,
                                                const float* __restrict__ bias,
                                                float* __restrict__ outp) {
  __shared__ u16 As[128 * 32];
  __shared__ u16 Bs[128 * 32];
  const int tid = threadIdx.x;
  const int lane = tid & 63, wave = tid >> 6;
  const int wr = wave >> 1, wc = wave & 1;
  const int m0 = blockIdx.y * 128, n0 = blockIdx.x * 128;

  f32x4 acc[4][4];
#pragma unroll
  for (int m = 0; m < 4; ++m)
#pragma unroll
    for (int n = 0; n < 4; ++n) acc[m][n] = (f32x4){0.f, 0.f, 0.f, 0.f};

  const int srow = wave * 32 + (lane >> 2);
  const int scol = (lane & 3) * 8;
  const u16* gA = A + (size_t)(m0 + srow) * DM + scol;
  const u16* gB = Bw + (size_t)(n0 + srow) * DM + scol;
  u16* lA = &As[wave * 32 * 32];
  u16* lB = &Bs[wave * 32 * 32];
  const int fr = lane & 15;
  const int k8 = (lane >> 4) * 8;

  for (int k0 = 0; k0 < DM; k0 += 32) {
    __syncthreads();
    gload_lds16(gA + k0, lA);
    gload_lds16(gA + k0 + 16 * DM, lA + 16 * 32);
    gload_lds16(gB + k0, lB);
    gload_lds16(gB + k0 + 16 * DM, lB + 16 * 32);
    __syncthreads();
    bf16x8 af[4], bfr[4];
#pragma unroll
    for (int m = 0; m < 4; ++m)
      af[m] = *(const bf16x8*)&As[(wr * 64 + m * 16 + fr) * 32 + k8];
#pragma unroll
    for (int n = 0; n < 4; ++n)
      bfr[n] = *(const bf16x8*)&Bs[(wc * 64 + n * 16 + fr) * 32 + k8];
#pragma unroll
    for (int m = 0; m < 4; ++m)
#pragma unroll
      for (int n = 0; n < 4; ++n)
        acc[m][n] = __builtin_amdgcn_mfma_f32_16x16x32_bf16(af[m], bfr[n], acc[m][n], 0, 0, 0);
  }

#pragma unroll
  for (int m = 0; m < 4; ++m) {
    const int rg = m0 + wr * 64 + m * 16 + (lane >> 4) * 4;
#pragma unroll
    for (int n = 0; n < 4; ++n) {
      const int cg = n0 + wc * 64 + n * 16 + fr;
      const float bb = bias[cg];
#pragma unroll
      for (int j = 0; j < 4; ++j)
        outp[(size_t)(rg + j) * DM + cg] = acc[m][n][j] + bb;
    }
  }
}

// ---------------- flash attention, causal, transposed-MFMA, P-in-register ------
// (unchanged from round 6)
__global__ __launch_bounds__(256) void attn_fwd(const u16* __restrict__ Q,
                                                const u16* __restrict__ K,
                                                const u16* __restrict__ Vt,
                                                u16* __restrict__ O) {
  const int pj = blockIdx.x, h = blockIdx.y, b = blockIdx.z;
  const int tid = threadIdx.x, lane = tid & 63, wave = tid >> 6;
  __shared__ u16 Ks[64 * 72];       // K rows [kv][d], padded stride 72
  __shared__ u16 Vs[64 * 72];       // V^T rows [d][perm-kv], padded stride 72

  const size_t bh = ((size_t)b * HEADS + h) * TT;
  const size_t vbse = ((size_t)b * HEADS + h) * DH;
  const int fr = lane & 15, g = lane >> 4, k8 = g * 8;
  const int sr = tid >> 2, sc = (tid & 3) * 8;

  for (int pass = 0; pass < 2; ++pass) {
    const int qt = pass ? pj : (NQT - 1 - pj);
    const int q0 = qt * 64;
    const int qrow = q0 + wave * 16 + fr;      // this lane's q-row
    const bf16x8 qf0 = *(const bf16x8*)&Q[(bh + qrow) * DH + k8];
    const bf16x8 qf1 = *(const bf16x8*)&Q[(bh + qrow) * DH + 32 + k8];

    float lsum = 0.f;
    f32x4 oacc[4];
#pragma unroll
    for (int c = 0; c < 4; ++c) oacc[c] = (f32x4){0.f, 0.f, 0.f, 0.f};

    for (int kvb = 0; kvb <= qt; ++kvb) {
      const int kv0 = kvb * 64;
      {
        const u16* kg = &K[(bh + kv0 + sr) * DH + sc];
        u16x8 ka = *(const u16x8*)kg;
        u16x8 kc = *(const u16x8*)(kg + 32);
        const u16* vg = &Vt[(vbse + sr) * TT + kv0 + sc];
        u16x8 va = *(const u16x8*)vg;
        u16x8 vc = *(const u16x8*)(vg + 32);
        *(u16x8*)&Ks[sr * 72 + sc] = ka;
        *(u16x8*)&Ks[sr * 72 + sc + 32] = kc;
        *(u16x8*)&Vs[sr * 72 + sc] = va;
        *(u16x8*)&Vs[sr * 72 + sc + 32] = vc;
      }
      __syncthreads();

      // S^T = K Q  (log2 domain; scale folded into Q)
      f32x4 s[4];
      __builtin_amdgcn_s_setprio(1);
#pragma unroll
      for (int c = 0; c < 4; ++c) {
        bf16x8 kb0 = *(const bf16x8*)&Ks[(c * 16 + fr) * 72 + k8];
        bf16x8 kb1 = *(const bf16x8*)&Ks[(c * 16 + fr) * 72 + 32 + k8];
        f32x4 t = (f32x4){0.f, 0.f, 0.f, 0.f};
        t = __builtin_amdgcn_mfma_f32_16x16x32_bf16(kb0, qf0, t, 0, 0, 0);
        t = __builtin_amdgcn_mfma_f32_16x16x32_bf16(kb1, qf1, t, 0, 0, 0);
        s[c] = t;
      }
      __builtin_amdgcn_s_setprio(0);

      if (kvb == qt) {  // diagonal tile: causal mask (in-lane, row = qrow)
#pragma unroll
        for (int c = 0; c < 4; ++c) {
          const int colg = kv0 + c * 16 + 4 * g;
#pragma unroll
          for (int r = 0; r < 4; ++r)
            if (colg + r > qrow) s[c][r] = -1e30f;
        }
      }

      // p = exp2(s), packed in-register; row-sum
      float rs = 0.f;
      uint32_t pk[8];
#pragma unroll
      for (int c = 0; c < 4; ++c) {
        float p0 = __builtin_amdgcn_exp2f(s[c][0]);
        float p1 = __builtin_amdgcn_exp2f(s[c][1]);
        float p2 = __builtin_amdgcn_exp2f(s[c][2]);
        float p3 = __builtin_amdgcn_exp2f(s[c][3]);
        rs += (p0 + p1) + (p2 + p3);
        pk[2 * c] = cvtpk(p0, p1);
        pk[2 * c + 1] = cvtpk(p2, p3);
      }
      rs += __shfl_xor(rs, 16);
      rs += __shfl_xor(rs, 32);
      lsum += rs;

      const bf16x8 pa0 = __builtin_bit_cast(bf16x8, (u32x4){pk[0], pk[1], pk[2], pk[3]});
      const bf16x8 pa1 = __builtin_bit_cast(bf16x8, (u32x4){pk[4], pk[5], pk[6], pk[7]});

      // O^T += V^T P^T   (b128 reads; V columns pre-permuted to match pa slots)
      __builtin_amdgcn_s_setprio(1);
#pragma unroll
      for (int c = 0; c < 4; ++c) {
        bf16x8 vb0 = *(const bf16x8*)&Vs[(c * 16 + fr) * 72 + k8];
        bf16x8 vb1 = *(const bf16x8*)&Vs[(c * 16 + fr) * 72 + 32 + k8];
        oacc[c] = __builtin_amdgcn_mfma_f32_16x16x32_bf16(vb0, pa0, oacc[c], 0, 0, 0);
        oacc[c] = __builtin_amdgcn_mfma_f32_16x16x32_bf16(vb1, pa1, oacc[c], 0, 0, 0);
      }
      __builtin_amdgcn_s_setprio(0);
      __syncthreads();
    }

    // epilogue: lane owns O[qrow][d = c*16 + 4g + r] -> packed ushort4 stores
    const float inv = 1.f / lsum;
#pragma unroll
    for (int c = 0; c < 4; ++c) {
      ushort4 o;
      o.x = f2b(oacc[c][0] * inv);
      o.y = f2b(oacc[c][1] * inv);
      o.z = f2b(oacc[c][2] * inv);
      o.w = f2b(oacc[c][3] * inv);
      *(ushort4*)&O[((size_t)b * TT + qrow) * DM + h * DH + c * 16 + 4 * g] = o;
    }
  }
}

extern "C" void kernel_launch(void* const* d_in, const int* in_sizes, int n_in,
                              void* d_out, int out_size, void* d_ws, size_t ws_size,
                              hipStream_t stream) {
  const float* x  = (const float*)d_in[0];
  const float* Wq = (const float*)d_in[1];
  const float* bq = (const float*)d_in[2];
  const float* Wk = (const float*)d_in[3];
  const float* bk = (const float*)d_in[4];
  const float* Wv = (const float*)d_in[5];
  const float* bv = (const float*)d_in[6];
  const float* Wo = (const float*)d_in[7];
  const float* bo = (const float*)d_in[8];

  char* w = (char*)d_ws;
  u16* xb    = (u16*)w; w += (size_t)MTOT * DM * 2;
  u16* Wqkvb = (u16*)w; w += (size_t)3 * DM * DM * 2;
  u16* Wob   = (u16*)w; w += (size_t)DM * DM * 2;
  u16* Qb    = (u16*)w; w += (size_t)MTOT * DM * 2;
  u16* Kb    = (u16*)w; w += (size_t)MTOT * DM * 2;
  u16* Vtb   = (u16*)w; w += (size_t)MTOT * DM * 2;
  u16* AOb   = (u16*)w; w += (size_t)MTOT * DM * 2;

  cast_f32_bf16<<<MTOT * DM / 4 / 256, 256, 0, stream>>>(x, xb, MTOT * DM / 4);
  cast_w3<<<3 * DM * DM / 4 / 256, 256, 0, stream>>>(Wq, Wk, Wv, Wqkvb);
  cast_f32_bf16<<<DM * DM / 4 / 256, 256, 0, stream>>>(Wo, Wob, DM * DM / 4);

  const float qs = 0.125f * 1.44269504f;  // 1/sqrt(64) * log2(e), folded into Q
  gemm_qkv8<<<384, 512, 0, stream>>>(xb, Wqkvb, bq, bk, bv, Qb, Kb, Vtb, qs);

  attn_fwd<<<dim3(NQT / 2, HEADS, BQ), 256, 0, stream>>>(Qb, Kb, Vtb, AOb);

  gemm_out<<<dim3(DM / 128, MTOT / 128), 256, 0, stream>>>(AOb, Wob, bo, (float*)d_out);
}

// Round 9
// 170.461 us; speedup vs baseline: 1.2763x; 1.0837x over previous
//
#include <hip/hip_runtime.h>
#include <stdint.h>

#define DM 1024
#define HEADS 16
#define DH 64
#define BQ 4
#define TT 2048
#define MTOT (BQ*TT)  // 8192
#define NQT (TT/64)   // 32 q-tiles per (b,h)

typedef __attribute__((ext_vector_type(8))) __bf16 bf16x8;
typedef __attribute__((ext_vector_type(4))) float f32x4;
typedef __attribute__((ext_vector_type(4))) uint32_t u32x4;
typedef unsigned short u16;
typedef __attribute__((ext_vector_type(8))) unsigned short u16x8;

__device__ __forceinline__ u16 f2b(float f) {
  uint32_t u = __builtin_bit_cast(uint32_t, f);
  u = (u + 0x7fffu + ((u >> 16) & 1u)) >> 16;
  return (u16)u;
}

__device__ __forceinline__ uint32_t cvtpk(float lo, float hi) {
  uint32_t r;
  asm("v_cvt_pk_bf16_f32 %0, %1, %2" : "=v"(r) : "v"(lo), "v"(hi));
  return r;
}

__device__ __forceinline__ void gload_lds16(const u16* g, u16* l) {
  __builtin_amdgcn_global_load_lds(
      (const __attribute__((address_space(1))) void*)g,
      (__attribute__((address_space(3))) void*)l, 16, 0, 0);
}

// ---------------- fused cast: x, Wq|Wk|Wv (contiguous), Wo -> bf16 ----------------
#define NX (MTOT * DM / 4)   // float4s in x
#define NW (DM * DM / 4)     // float4s per weight matrix
__global__ __launch_bounds__(256) void cast_all(const float* __restrict__ x,
                                                const float* __restrict__ Wq,
                                                const float* __restrict__ Wk,
                                                const float* __restrict__ Wv,
                                                const float* __restrict__ Wo,
                                                u16* __restrict__ xb,
                                                u16* __restrict__ wqkvb,
                                                u16* __restrict__ wob) {
  int i = blockIdx.x * 256 + threadIdx.x;
  const float* src; u16* dst;
  if (i < NX)               { src = x;  dst = xb; }
  else if (i < NX + NW)     { src = Wq; dst = wqkvb;          i -= NX; }
  else if (i < NX + 2 * NW) { src = Wk; dst = wqkvb + 4 * NW; i -= NX + NW; }
  else if (i < NX + 3 * NW) { src = Wv; dst = wqkvb + 8 * NW; i -= NX + 2 * NW; }
  else                      { src = Wo; dst = wob;            i -= NX + 3 * NW; }
  float4 v = ((const float4*)src)[i];
  ushort4 o;
  o.x = f2b(v.x); o.y = f2b(v.y); o.z = f2b(v.z); o.w = f2b(v.w);
  ((ushort4*)dst)[i] = o;
}

// ---------------- fused QKV GEMM, 256x256 tile, counted-vmcnt + reg dbuf ------
// (unchanged from round 8)
#define BKq 32
#define NKq (DM / BKq)          // 32 K-tiles
#define SLOT_A (256 * BKq)      // 8192 elems (16KB)
#define SLOT_E (2 * SLOT_A)     // 16384 elems (32KB) per slot

__global__ __launch_bounds__(512, 2) void gemm_qkv8(const u16* __restrict__ A,
                                                    const u16* __restrict__ W,
                                                    const float* __restrict__ bq,
                                                    const float* __restrict__ bk,
                                                    const float* __restrict__ bv,
                                                    u16* __restrict__ Qo,
                                                    u16* __restrict__ Ko,
                                                    u16* __restrict__ Vto,
                                                    float qs) {
  __shared__ u16 lds[4 * SLOT_E];  // 128 KB
  const int tid = threadIdx.x, lane = tid & 63, wave = tid >> 6;
  const int fr = lane & 15, g = lane >> 4;
  const int wm = wave >> 2, wn = wave & 3;

  // T1: bijective XCD swizzle (384 blocks, 384 % 8 == 0)
  int bid = blockIdx.x;
  bid = (bid & 7) * 48 + (bid >> 3);
  const int bx = bid % 12, by = bid / 12;     // bx: n-tile, by: m-tile
  const int m0 = by * 256, n0 = bx * 256;

  const int srow = tid >> 2;                               // 0..127
  const int schunk = (tid & 3) ^ ((tid >> 3) & 3);         // swizzled 16B chunk
  const u16* gA0 = A + (size_t)(m0 + srow) * DM + schunk * 8;
  const u16* gA1 = gA0 + (size_t)128 * DM;
  const u16* gB0 = W + (size_t)(n0 + srow) * DM + schunk * 8;
  const u16* gB1 = gB0 + (size_t)128 * DM;
  const int dA0 = wave * 512;
  const int dA1 = 4096 + wave * 512;
  const int dB0 = SLOT_A + wave * 512;
  const int dB1 = SLOT_A + 4096 + wave * 512;

#define STAGEQ(slot, kt) {                                   \
    u16* ls = &lds[(slot) * SLOT_E];                         \
    const int ke = (kt) * BKq;                               \
    gload_lds16(gA0 + ke, ls + dA0);                         \
    gload_lds16(gA1 + ke, ls + dA1);                         \
    gload_lds16(gB0 + ke, ls + dB0);                         \
    gload_lds16(gB1 + ke, ls + dB1); }

  const int rchunk = (g ^ ((fr >> 1) & 3)) * 8;
  const int offA = (wm * 128 + fr) * 32 + rchunk;           // + mi*512
  const int offB = SLOT_A + (wn * 64 + fr) * 32 + rchunk;   // + ni*512

  f32x4 acc[8][4];
#pragma unroll
  for (int mi = 0; mi < 8; ++mi)
#pragma unroll
    for (int ni = 0; ni < 4; ++ni) acc[mi][ni] = (f32x4){0.f, 0.f, 0.f, 0.f};

  bf16x8 afA[8], bfA[4], afB[8], bfB[4];

#define READQ(AFv, BFv, kt) {                                \
    const u16* sl = &lds[((kt) & 3) * SLOT_E];               \
    _Pragma("unroll")                                        \
    for (int mi = 0; mi < 8; ++mi)                           \
      AFv[mi] = *(const bf16x8*)&sl[offA + mi * 512];        \
    _Pragma("unroll")                                        \
    for (int ni = 0; ni < 4; ++ni)                           \
      BFv[ni] = *(const bf16x8*)&sl[offB + ni * 512]; }

#define MFMAQ(AFv, BFv) {                                    \
    __builtin_amdgcn_s_setprio(1);                           \
    _Pragma("unroll")                                        \
    for (int mi = 0; mi < 8; ++mi)                           \
      _Pragma("unroll")                                      \
      for (int ni = 0; ni < 4; ++ni)                         \
        acc[mi][ni] = __builtin_amdgcn_mfma_f32_16x16x32_bf16(AFv[mi], BFv[ni], acc[mi][ni], 0, 0, 0); \
    __builtin_amdgcn_s_setprio(0); }

#define WAIT4 asm volatile("s_waitcnt vmcnt(4)" ::: "memory"); \
              asm volatile("s_barrier" ::: "memory");
#define WAIT0 asm volatile("s_waitcnt vmcnt(0)" ::: "memory"); \
              asm volatile("s_barrier" ::: "memory");

  STAGEQ(0, 0)
  STAGEQ(1, 1)
  STAGEQ(2, 2)
  asm volatile("s_waitcnt vmcnt(8)" ::: "memory");
  asm volatile("s_barrier" ::: "memory");
  READQ(afA, bfA, 0)

  for (int kt = 0; kt < NKq - 4; kt += 2) {
    WAIT4
    READQ(afB, bfB, kt + 1)
    MFMAQ(afA, bfA)
    STAGEQ((kt + 3) & 3, kt + 3)
    WAIT4
    READQ(afA, bfA, kt + 2)
    MFMAQ(afB, bfB)
    STAGEQ((kt + 4) & 3, kt + 4)
  }
  WAIT4
  READQ(afB, bfB, NKq - 3)
  MFMAQ(afA, bfA)
  STAGEQ((NKq - 1) & 3, NKq - 1)
  WAIT4
  READQ(afA, bfA, NKq - 2)
  MFMAQ(afB, bfB)
  WAIT0
  READQ(afB, bfB, NKq - 1)
  MFMAQ(afA, bfA)
  MFMAQ(afB, bfB)

  const int g4 = g * 4;
  const int seg = n0 >> 10;
  const int nbase = (n0 & 1023) + wn * 64 + fr;
  if (seg == 0) {
#pragma unroll
    for (int ni = 0; ni < 4; ++ni) {
      const int cgl = nbase + ni * 16;
      const float bb = bq[cgl];
      const int hh = cgl >> 6, d = cgl & 63;
#pragma unroll
      for (int mi = 0; mi < 8; ++mi) {
        const int m = m0 + wm * 128 + mi * 16 + g4;
        const int bi = m >> 11, t = m & 2047;
        u16* dst = &Qo[(((size_t)bi * HEADS + hh) * TT + t) * DH + d];
#pragma unroll
        for (int j = 0; j < 4; ++j)
          dst[(size_t)j * DH] = f2b((acc[mi][ni][j] + bb) * qs);
      }
    }
  } else if (seg == 1) {
#pragma unroll
    for (int ni = 0; ni < 4; ++ni) {
      const int cgl = nbase + ni * 16;
      const float bb = bk[cgl];
      const int hh = cgl >> 6, d = cgl & 63;
#pragma unroll
      for (int mi = 0; mi < 8; ++mi) {
        const int m = m0 + wm * 128 + mi * 16 + g4;
        const int bi = m >> 11, t = m & 2047;
        u16* dst = &Ko[(((size_t)bi * HEADS + hh) * TT + t) * DH + d];
#pragma unroll
        for (int j = 0; j < 4; ++j)
          dst[(size_t)j * DH] = f2b(acc[mi][ni][j] + bb);
      }
    }
  } else {
#pragma unroll
    for (int ni = 0; ni < 4; ++ni) {
      const int cgl = nbase + ni * 16;
      const float bb = bv[cgl];
      const int hh = cgl >> 6, d = cgl & 63;
#pragma unroll
      for (int mi = 0; mi < 8; ++mi) {
        const int t0 = (m0 + wm * 128 + mi * 16 + g4) & 2047;
        const int bi = (m0 + wm * 128 + mi * 16 + g4) >> 11;
        const int w64 = t0 & 63;
        const int pos = (t0 & ~63) | (((w64 >> 5) & 1) << 5) | (((w64 >> 2) & 3) << 3) |
                        (((w64 >> 4) & 1) << 2);
        ushort4 o;
        o.x = f2b(acc[mi][ni][0] + bb);
        o.y = f2b(acc[mi][ni][1] + bb);
        o.z = f2b(acc[mi][ni][2] + bb);
        o.w = f2b(acc[mi][ni][3] + bb);
        *(ushort4*)&Vto[(((size_t)bi * HEADS + hh) * DH + d) * TT + pos] = o;
      }
    }
  }
#undef STAGEQ
#undef READQ
#undef MFMAQ
#undef WAIT4
#undef WAIT0
}

// ---------------- O-projection GEMM: f32 out [M, DM] ----------------
__global__ __launch_bounds__(256) void gemm_out(const u16* __restrict__ A,
                                                const u16* __restrict__ Bw,
                                                const float* __restrict__ bias,
                                                float* __restrict__ outp) {
  __shared__ u16 As[128 * 32];
  __shared__ u16 Bs[128 * 32];
  const int tid = threadIdx.x;
  const int lane = tid & 63, wave = tid >> 6;
  const int wr = wave >> 1, wc = wave & 1;
  const int m0 = blockIdx.y * 128, n0 = blockIdx.x * 128;

  f32x4 acc[4][4];
#pragma unroll
  for (int m = 0; m < 4; ++m)
#pragma unroll
    for (int n = 0; n < 4; ++n) acc[m][n] = (f32x4){0.f, 0.f, 0.f, 0.f};

  const int srow = wave * 32 + (lane >> 2);
  const int scol = (lane & 3) * 8;
  const u16* gA = A + (size_t)(m0 + srow) * DM + scol;
  const u16* gB = Bw + (size_t)(n0 + srow) * DM + scol;
  u16* lA = &As[wave * 32 * 32];
  u16* lB = &Bs[wave * 32 * 32];
  const int fr = lane & 15;
  const int k8 = (lane >> 4) * 8;

  for (int k0 = 0; k0 < DM; k0 += 32) {
    __syncthreads();
    gload_lds16(gA + k0, lA);
    gload_lds16(gA + k0 + 16 * DM, lA + 16 * 32);
    gload_lds16(gB + k0, lB);
    gload_lds16(gB + k0 + 16 * DM, lB + 16 * 32);
    __syncthreads();
    bf16x8 af[4], bfr[4];
#pragma unroll
    for (int m = 0; m < 4; ++m)
      af[m] = *(const bf16x8*)&As[(wr * 64 + m * 16 + fr) * 32 + k8];
#pragma unroll
    for (int n = 0; n < 4; ++n)
      bfr[n] = *(const bf16x8*)&Bs[(wc * 64 + n * 16 + fr) * 32 + k8];
#pragma unroll
    for (int m = 0; m < 4; ++m)
#pragma unroll
      for (int n = 0; n < 4; ++n)
        acc[m][n] = __builtin_amdgcn_mfma_f32_16x16x32_bf16(af[m], bfr[n], acc[m][n], 0, 0, 0);
  }

#pragma unroll
  for (int m = 0; m < 4; ++m) {
    const int rg = m0 + wr * 64 + m * 16 + (lane >> 4) * 4;
#pragma unroll
    for (int n = 0; n < 4; ++n) {
      const int cg = n0 + wc * 64 + n * 16 + fr;
      const float bb = bias[cg];
#pragma unroll
      for (int j = 0; j < 4; ++j)
        outp[(size_t)(rg + j) * DM + cg] = acc[m][n][j] + bb;
    }
  }
}

// ---------------- flash attention, causal, transposed-MFMA, P-in-register ------
// Grid: 1024 linear blocks, XCD-locality decode: all 16 pj-blocks of one (b,h)
// land on the same XCD (assuming dispatch xcd = blockIdx % 8), so the group's
// K/V working set (512 KB) stays resident in that XCD's 4 MB L2.
__global__ __launch_bounds__(256) void attn_fwd(const u16* __restrict__ Q,
                                                const u16* __restrict__ K,
                                                const u16* __restrict__ Vt,
                                                u16* __restrict__ O) {
  const int o_ = blockIdx.x;
  const int r_ = o_ & 7, q_ = o_ >> 3;
  const int gidx = r_ * 8 + (q_ >> 4);     // (b,h) group 0..63
  const int pj = q_ & 15;
  const int b = gidx >> 4, h = gidx & 15;
  const int tid = threadIdx.x, lane = tid & 63, wave = tid >> 6;
  __shared__ u16 Ks[64 * 72];       // K rows [kv][d], padded stride 72
  __shared__ u16 Vs[64 * 72];       // V^T rows [d][perm-kv], padded stride 72

  const size_t bh = ((size_t)b * HEADS + h) * TT;
  const size_t vbse = ((size_t)b * HEADS + h) * DH;
  const int fr = lane & 15, g = lane >> 4, k8 = g * 8;
  const int sr = tid >> 2, sc = (tid & 3) * 8;

  for (int pass = 0; pass < 2; ++pass) {
    const int qt = pass ? pj : (NQT - 1 - pj);
    const int q0 = qt * 64;
    const int qrow = q0 + wave * 16 + fr;      // this lane's q-row
    const bf16x8 qf0 = *(const bf16x8*)&Q[(bh + qrow) * DH + k8];
    const bf16x8 qf1 = *(const bf16x8*)&Q[(bh + qrow) * DH + 32 + k8];

    float lsum = 0.f;
    f32x4 oacc[4];
#pragma unroll
    for (int c = 0; c < 4; ++c) oacc[c] = (f32x4){0.f, 0.f, 0.f, 0.f};

    for (int kvb = 0; kvb <= qt; ++kvb) {
      const int kv0 = kvb * 64;
      {
        const u16* kg = &K[(bh + kv0 + sr) * DH + sc];
        u16x8 ka = *(const u16x8*)kg;
        u16x8 kc = *(const u16x8*)(kg + 32);
        const u16* vg = &Vt[(vbse + sr) * TT + kv0 + sc];
        u16x8 va = *(const u16x8*)vg;
        u16x8 vc = *(const u16x8*)(vg + 32);
        *(u16x8*)&Ks[sr * 72 + sc] = ka;
        *(u16x8*)&Ks[sr * 72 + sc + 32] = kc;
        *(u16x8*)&Vs[sr * 72 + sc] = va;
        *(u16x8*)&Vs[sr * 72 + sc + 32] = vc;
      }
      __syncthreads();

      // S^T = K Q  (log2 domain; scale folded into Q)
      f32x4 s[4];
      __builtin_amdgcn_s_setprio(1);
#pragma unroll
      for (int c = 0; c < 4; ++c) {
        bf16x8 kb0 = *(const bf16x8*)&Ks[(c * 16 + fr) * 72 + k8];
        bf16x8 kb1 = *(const bf16x8*)&Ks[(c * 16 + fr) * 72 + 32 + k8];
        f32x4 t = (f32x4){0.f, 0.f, 0.f, 0.f};
        t = __builtin_amdgcn_mfma_f32_16x16x32_bf16(kb0, qf0, t, 0, 0, 0);
        t = __builtin_amdgcn_mfma_f32_16x16x32_bf16(kb1, qf1, t, 0, 0, 0);
        s[c] = t;
      }
      __builtin_amdgcn_s_setprio(0);

      if (kvb == qt) {  // diagonal tile: causal mask (in-lane, row = qrow)
#pragma unroll
        for (int c = 0; c < 4; ++c) {
          const int colg = kv0 + c * 16 + 4 * g;
#pragma unroll
          for (int r = 0; r < 4; ++r)
            if (colg + r > qrow) s[c][r] = -1e30f;
        }
      }

      // p = exp2(s), packed in-register; row-sum
      float rs = 0.f;
      uint32_t pk[8];
#pragma unroll
      for (int c = 0; c < 4; ++c) {
        float p0 = __builtin_amdgcn_exp2f(s[c][0]);
        float p1 = __builtin_amdgcn_exp2f(s[c][1]);
        float p2 = __builtin_amdgcn_exp2f(s[c][2]);
        float p3 = __builtin_amdgcn_exp2f(s[c][3]);
        rs += (p0 + p1) + (p2 + p3);
        pk[2 * c] = cvtpk(p0, p1);
        pk[2 * c + 1] = cvtpk(p2, p3);
      }
      rs += __shfl_xor(rs, 16);
      rs += __shfl_xor(rs, 32);
      lsum += rs;

      const bf16x8 pa0 = __builtin_bit_cast(bf16x8, (u32x4){pk[0], pk[1], pk[2], pk[3]});
      const bf16x8 pa1 = __builtin_bit_cast(bf16x8, (u32x4){pk[4], pk[5], pk[6], pk[7]});

      // O^T += V^T P^T   (b128 reads; V columns pre-permuted to match pa slots)
      __builtin_amdgcn_s_setprio(1);
#pragma unroll
      for (int c = 0; c < 4; ++c) {
        bf16x8 vb0 = *(const bf16x8*)&Vs[(c * 16 + fr) * 72 + k8];
        bf16x8 vb1 = *(const bf16x8*)&Vs[(c * 16 + fr) * 72 + 32 + k8];
        oacc[c] = __builtin_amdgcn_mfma_f32_16x16x32_bf16(vb0, pa0, oacc[c], 0, 0, 0);
        oacc[c] = __builtin_amdgcn_mfma_f32_16x16x32_bf16(vb1, pa1, oacc[c], 0, 0, 0);
      }
      __builtin_amdgcn_s_setprio(0);
      __syncthreads();
    }

    // epilogue: lane owns O[qrow][d = c*16 + 4g + r] -> packed ushort4 stores
    const float inv = 1.f / lsum;
#pragma unroll
    for (int c = 0; c < 4; ++c) {
      ushort4 o;
      o.x = f2b(oacc[c][0] * inv);
      o.y = f2b(oacc[c][1] * inv);
      o.z = f2b(oacc[c][2] * inv);
      o.w = f2b(oacc[c][3] * inv);
      *(ushort4*)&O[((size_t)b * TT + qrow) * DM + h * DH + c * 16 + 4 * g] = o;
    }
  }
}

extern "C" void kernel_launch(void* const* d_in, const int* in_sizes, int n_in,
                              void* d_out, int out_size, void* d_ws, size_t ws_size,
                              hipStream_t stream) {
  const float* x  = (const float*)d_in[0];
  const float* Wq = (const float*)d_in[1];
  const float* bq = (const float*)d_in[2];
  const float* Wk = (const float*)d_in[3];
  const float* bk = (const float*)d_in[4];
  const float* Wv = (const float*)d_in[5];
  const float* bv = (const float*)d_in[6];
  const float* Wo = (const float*)d_in[7];
  const float* bo = (const float*)d_in[8];

  char* w = (char*)d_ws;
  u16* xb    = (u16*)w; w += (size_t)MTOT * DM * 2;
  u16* Wqkvb = (u16*)w; w += (size_t)3 * DM * DM * 2;
  u16* Wob   = (u16*)w; w += (size_t)DM * DM * 2;
  u16* Qb    = (u16*)w; w += (size_t)MTOT * DM * 2;
  u16* Kb    = (u16*)w; w += (size_t)MTOT * DM * 2;
  u16* Vtb   = (u16*)w; w += (size_t)MTOT * DM * 2;
  u16* AOb   = (u16*)w; w += (size_t)MTOT * DM * 2;

  cast_all<<<(NX + 4 * NW) / 256, 256, 0, stream>>>(x, Wq, Wk, Wv, Wo, xb, Wqkvb, Wob);

  const float qs = 0.125f * 1.44269504f;  // 1/sqrt(64) * log2(e), folded into Q
  gemm_qkv8<<<384, 512, 0, stream>>>(xb, Wqkvb, bq, bk, bv, Qb, Kb, Vtb, qs);

  attn_fwd<<<1024, 256, 0, stream>>>(Qb, Kb, Vtb, AOb);

  gemm_out<<<dim3(DM / 128, MTOT / 128), 256, 0, stream>>>(AOb, Wob, bo, (float*)d_out);
}

// Round 10
// 166.300 us; speedup vs baseline: 1.3082x; 1.0250x over previous
//
#include <hip/hip_runtime.h>
#include <stdint.h>

#define DM 1024
#define HEADS 16
#define DH 64
#define BQ 4
#define TT 2048
#define MTOT (BQ*TT)  // 8192
#define NQT (TT/64)   // 32 q-tiles per (b,h)

typedef __attribute__((ext_vector_type(8))) __bf16 bf16x8;
typedef __attribute__((ext_vector_type(4))) float f32x4;
typedef __attribute__((ext_vector_type(4))) uint32_t u32x4;
typedef unsigned short u16;
typedef __attribute__((ext_vector_type(8))) unsigned short u16x8;

__device__ __forceinline__ u16 f2b(float f) {
  uint32_t u = __builtin_bit_cast(uint32_t, f);
  u = (u + 0x7fffu + ((u >> 16) & 1u)) >> 16;
  return (u16)u;
}

__device__ __forceinline__ uint32_t cvtpk(float lo, float hi) {
  uint32_t r;
  asm("v_cvt_pk_bf16_f32 %0, %1, %2" : "=v"(r) : "v"(lo), "v"(hi));
  return r;
}

__device__ __forceinline__ void gload_lds16(const u16* g, u16* l) {
  __builtin_amdgcn_global_load_lds(
      (const __attribute__((address_space(1))) void*)g,
      (__attribute__((address_space(3))) void*)l, 16, 0, 0);
}

// ---------------- fused cast: x, Wq|Wk|Wv (contiguous), Wo -> bf16 ----------------
#define NX (MTOT * DM / 4)   // float4s in x
#define NW (DM * DM / 4)     // float4s per weight matrix
__global__ __launch_bounds__(256) void cast_all(const float* __restrict__ x,
                                                const float* __restrict__ Wq,
                                                const float* __restrict__ Wk,
                                                const float* __restrict__ Wv,
                                                const float* __restrict__ Wo,
                                                u16* __restrict__ xb,
                                                u16* __restrict__ wqkvb,
                                                u16* __restrict__ wob) {
  int i = blockIdx.x * 256 + threadIdx.x;
  const float* src; u16* dst;
  if (i < NX)               { src = x;  dst = xb; }
  else if (i < NX + NW)     { src = Wq; dst = wqkvb;          i -= NX; }
  else if (i < NX + 2 * NW) { src = Wk; dst = wqkvb + 4 * NW; i -= NX + NW; }
  else if (i < NX + 3 * NW) { src = Wv; dst = wqkvb + 8 * NW; i -= NX + 2 * NW; }
  else                      { src = Wo; dst = wob;            i -= NX + 3 * NW; }
  float4 v = ((const float4*)src)[i];
  ushort4 o;
  o.x = f2b(v.x); o.y = f2b(v.y); o.z = f2b(v.z); o.w = f2b(v.w);
  ((ushort4*)dst)[i] = o;
}

// ---------------- fused QKV GEMM, 256x256 tile, counted-vmcnt + reg dbuf ------
// (unchanged from round 8)
#define BKq 32
#define NKq (DM / BKq)          // 32 K-tiles
#define SLOT_A (256 * BKq)      // 8192 elems (16KB)
#define SLOT_E (2 * SLOT_A)     // 16384 elems (32KB) per slot

__global__ __launch_bounds__(512, 2) void gemm_qkv8(const u16* __restrict__ A,
                                                    const u16* __restrict__ W,
                                                    const float* __restrict__ bq,
                                                    const float* __restrict__ bk,
                                                    const float* __restrict__ bv,
                                                    u16* __restrict__ Qo,
                                                    u16* __restrict__ Ko,
                                                    u16* __restrict__ Vto,
                                                    float qs) {
  __shared__ u16 lds[4 * SLOT_E];  // 128 KB
  const int tid = threadIdx.x, lane = tid & 63, wave = tid >> 6;
  const int fr = lane & 15, g = lane >> 4;
  const int wm = wave >> 2, wn = wave & 3;

  // T1: bijective XCD swizzle (384 blocks, 384 % 8 == 0)
  int bid = blockIdx.x;
  bid = (bid & 7) * 48 + (bid >> 3);
  const int bx = bid % 12, by = bid / 12;     // bx: n-tile, by: m-tile
  const int m0 = by * 256, n0 = bx * 256;

  const int srow = tid >> 2;                               // 0..127
  const int schunk = (tid & 3) ^ ((tid >> 3) & 3);         // swizzled 16B chunk
  const u16* gA0 = A + (size_t)(m0 + srow) * DM + schunk * 8;
  const u16* gA1 = gA0 + (size_t)128 * DM;
  const u16* gB0 = W + (size_t)(n0 + srow) * DM + schunk * 8;
  const u16* gB1 = gB0 + (size_t)128 * DM;
  const int dA0 = wave * 512;
  const int dA1 = 4096 + wave * 512;
  const int dB0 = SLOT_A + wave * 512;
  const int dB1 = SLOT_A + 4096 + wave * 512;

#define STAGEQ(slot, kt) {                                   \
    u16* ls = &lds[(slot) * SLOT_E];                         \
    const int ke = (kt) * BKq;                               \
    gload_lds16(gA0 + ke, ls + dA0);                         \
    gload_lds16(gA1 + ke, ls + dA1);                         \
    gload_lds16(gB0 + ke, ls + dB0);                         \
    gload_lds16(gB1 + ke, ls + dB1); }

  const int rchunk = (g ^ ((fr >> 1) & 3)) * 8;
  const int offA = (wm * 128 + fr) * 32 + rchunk;           // + mi*512
  const int offB = SLOT_A + (wn * 64 + fr) * 32 + rchunk;   // + ni*512

  f32x4 acc[8][4];
#pragma unroll
  for (int mi = 0; mi < 8; ++mi)
#pragma unroll
    for (int ni = 0; ni < 4; ++ni) acc[mi][ni] = (f32x4){0.f, 0.f, 0.f, 0.f};

  bf16x8 afA[8], bfA[4], afB[8], bfB[4];

#define READQ(AFv, BFv, kt) {                                \
    const u16* sl = &lds[((kt) & 3) * SLOT_E];               \
    _Pragma("unroll")                                        \
    for (int mi = 0; mi < 8; ++mi)                           \
      AFv[mi] = *(const bf16x8*)&sl[offA + mi * 512];        \
    _Pragma("unroll")                                        \
    for (int ni = 0; ni < 4; ++ni)                           \
      BFv[ni] = *(const bf16x8*)&sl[offB + ni * 512]; }

#define MFMAQ(AFv, BFv) {                                    \
    __builtin_amdgcn_s_setprio(1);                           \
    _Pragma("unroll")                                        \
    for (int mi = 0; mi < 8; ++mi)                           \
      _Pragma("unroll")                                      \
      for (int ni = 0; ni < 4; ++ni)                         \
        acc[mi][ni] = __builtin_amdgcn_mfma_f32_16x16x32_bf16(AFv[mi], BFv[ni], acc[mi][ni], 0, 0, 0); \
    __builtin_amdgcn_s_setprio(0); }

#define WAIT4 asm volatile("s_waitcnt vmcnt(4)" ::: "memory"); \
              asm volatile("s_barrier" ::: "memory");
#define WAIT0 asm volatile("s_waitcnt vmcnt(0)" ::: "memory"); \
              asm volatile("s_barrier" ::: "memory");

  STAGEQ(0, 0)
  STAGEQ(1, 1)
  STAGEQ(2, 2)
  asm volatile("s_waitcnt vmcnt(8)" ::: "memory");
  asm volatile("s_barrier" ::: "memory");
  READQ(afA, bfA, 0)

  for (int kt = 0; kt < NKq - 4; kt += 2) {
    WAIT4
    READQ(afB, bfB, kt + 1)
    MFMAQ(afA, bfA)
    STAGEQ((kt + 3) & 3, kt + 3)
    WAIT4
    READQ(afA, bfA, kt + 2)
    MFMAQ(afB, bfB)
    STAGEQ((kt + 4) & 3, kt + 4)
  }
  WAIT4
  READQ(afB, bfB, NKq - 3)
  MFMAQ(afA, bfA)
  STAGEQ((NKq - 1) & 3, NKq - 1)
  WAIT4
  READQ(afA, bfA, NKq - 2)
  MFMAQ(afB, bfB)
  WAIT0
  READQ(afB, bfB, NKq - 1)
  MFMAQ(afA, bfA)
  MFMAQ(afB, bfB)

  const int g4 = g * 4;
  const int seg = n0 >> 10;
  const int nbase = (n0 & 1023) + wn * 64 + fr;
  if (seg == 0) {
#pragma unroll
    for (int ni = 0; ni < 4; ++ni) {
      const int cgl = nbase + ni * 16;
      const float bb = bq[cgl];
      const int hh = cgl >> 6, d = cgl & 63;
#pragma unroll
      for (int mi = 0; mi < 8; ++mi) {
        const int m = m0 + wm * 128 + mi * 16 + g4;
        const int bi = m >> 11, t = m & 2047;
        u16* dst = &Qo[(((size_t)bi * HEADS + hh) * TT + t) * DH + d];
#pragma unroll
        for (int j = 0; j < 4; ++j)
          dst[(size_t)j * DH] = f2b((acc[mi][ni][j] + bb) * qs);
      }
    }
  } else if (seg == 1) {
#pragma unroll
    for (int ni = 0; ni < 4; ++ni) {
      const int cgl = nbase + ni * 16;
      const float bb = bk[cgl];
      const int hh = cgl >> 6, d = cgl & 63;
#pragma unroll
      for (int mi = 0; mi < 8; ++mi) {
        const int m = m0 + wm * 128 + mi * 16 + g4;
        const int bi = m >> 11, t = m & 2047;
        u16* dst = &Ko[(((size_t)bi * HEADS + hh) * TT + t) * DH + d];
#pragma unroll
        for (int j = 0; j < 4; ++j)
          dst[(size_t)j * DH] = f2b(acc[mi][ni][j] + bb);
      }
    }
  } else {
#pragma unroll
    for (int ni = 0; ni < 4; ++ni) {
      const int cgl = nbase + ni * 16;
      const float bb = bv[cgl];
      const int hh = cgl >> 6, d = cgl & 63;
#pragma unroll
      for (int mi = 0; mi < 8; ++mi) {
        const int t0 = (m0 + wm * 128 + mi * 16 + g4) & 2047;
        const int bi = (m0 + wm * 128 + mi * 16 + g4) >> 11;
        const int w64 = t0 & 63;
        const int pos = (t0 & ~63) | (((w64 >> 5) & 1) << 5) | (((w64 >> 2) & 3) << 3) |
                        (((w64 >> 4) & 1) << 2);
        ushort4 o;
        o.x = f2b(acc[mi][ni][0] + bb);
        o.y = f2b(acc[mi][ni][1] + bb);
        o.z = f2b(acc[mi][ni][2] + bb);
        o.w = f2b(acc[mi][ni][3] + bb);
        *(ushort4*)&Vto[(((size_t)bi * HEADS + hh) * DH + d) * TT + pos] = o;
      }
    }
  }
#undef STAGEQ
#undef READQ
#undef MFMAQ
#undef WAIT4
#undef WAIT0
}

// ---------------- O-projection GEMM: f32 out [M, DM] ----------------
__global__ __launch_bounds__(256) void gemm_out(const u16* __restrict__ A,
                                                const u16* __restrict__ Bw,
                                                const float* __restrict__ bias,
                                                float* __restrict__ outp) {
  __shared__ u16 As[128 * 32];
  __shared__ u16 Bs[128 * 32];
  const int tid = threadIdx.x;
  const int lane = tid & 63, wave = tid >> 6;
  const int wr = wave >> 1, wc = wave & 1;
  const int m0 = blockIdx.y * 128, n0 = blockIdx.x * 128;

  f32x4 acc[4][4];
#pragma unroll
  for (int m = 0; m < 4; ++m)
#pragma unroll
    for (int n = 0; n < 4; ++n) acc[m][n] = (f32x4){0.f, 0.f, 0.f, 0.f};

  const int srow = wave * 32 + (lane >> 2);
  const int scol = (lane & 3) * 8;
  const u16* gA = A + (size_t)(m0 + srow) * DM + scol;
  const u16* gB = Bw + (size_t)(n0 + srow) * DM + scol;
  u16* lA = &As[wave * 32 * 32];
  u16* lB = &Bs[wave * 32 * 32];
  const int fr = lane & 15;
  const int k8 = (lane >> 4) * 8;

  for (int k0 = 0; k0 < DM; k0 += 32) {
    __syncthreads();
    gload_lds16(gA + k0, lA);
    gload_lds16(gA + k0 + 16 * DM, lA + 16 * 32);
    gload_lds16(gB + k0, lB);
    gload_lds16(gB + k0 + 16 * DM, lB + 16 * 32);
    __syncthreads();
    bf16x8 af[4], bfr[4];
#pragma unroll
    for (int m = 0; m < 4; ++m)
      af[m] = *(const bf16x8*)&As[(wr * 64 + m * 16 + fr) * 32 + k8];
#pragma unroll
    for (int n = 0; n < 4; ++n)
      bfr[n] = *(const bf16x8*)&Bs[(wc * 64 + n * 16 + fr) * 32 + k8];
#pragma unroll
    for (int m = 0; m < 4; ++m)
#pragma unroll
      for (int n = 0; n < 4; ++n)
        acc[m][n] = __builtin_amdgcn_mfma_f32_16x16x32_bf16(af[m], bfr[n], acc[m][n], 0, 0, 0);
  }

#pragma unroll
  for (int m = 0; m < 4; ++m) {
    const int rg = m0 + wr * 64 + m * 16 + (lane >> 4) * 4;
#pragma unroll
    for (int n = 0; n < 4; ++n) {
      const int cg = n0 + wc * 64 + n * 16 + fr;
      const float bb = bias[cg];
#pragma unroll
      for (int j = 0; j < 4; ++j)
        outp[(size_t)(rg + j) * DM + cg] = acc[m][n][j] + bb;
    }
  }
}

// ---------------- flash attention, causal, transposed-MFMA, P-in-register ------
// XCD-local grid decode (round 9).  NEW: unpadded [64][64] K/V LDS tiles with
// 16B-chunk XOR swizzle (chunk ^= row&7) on BOTH write and read sides — rows
// are bank-aligned (128B stride) and the 64 lanes of every b128 read/write
// spread 8 lanes per 16B bank-group (optimal; same scheme measured 0 conflicts
// in gemm_qkv8).  Read-side XOR reduces to fr&7 since row = c*16+fr.
__global__ __launch_bounds__(256) void attn_fwd(const u16* __restrict__ Q,
                                                const u16* __restrict__ K,
                                                const u16* __restrict__ Vt,
                                                u16* __restrict__ O) {
  const int o_ = blockIdx.x;
  const int r_ = o_ & 7, q_ = o_ >> 3;
  const int gidx = r_ * 8 + (q_ >> 4);     // (b,h) group 0..63
  const int pj = q_ & 15;
  const int b = gidx >> 4, h = gidx & 15;
  const int tid = threadIdx.x, lane = tid & 63, wave = tid >> 6;
  __shared__ u16 Ks[64 * 64];       // K rows [kv][d], XOR-swizzled chunks
  __shared__ u16 Vs[64 * 64];       // V^T rows [d][perm-kv], XOR-swizzled chunks

  const size_t bh = ((size_t)b * HEADS + h) * TT;
  const size_t vbse = ((size_t)b * HEADS + h) * DH;
  const int fr = lane & 15, g = lane >> 4;
  const int sr = tid >> 2;                 // staging row 0..63
  const int sc0 = tid & 3;                 // base 16B chunk 0..3

  // swizzled staging chunk offsets (elements)
  const int sw1 = (sc0 ^ (sr & 7)) * 8;
  const int sw2 = ((sc0 + 4) ^ (sr & 7)) * 8;
  const int sgc = sc0 * 8;                 // global source column (elems)
  // swizzled read chunk offsets: row = c*16+fr  ->  row&7 == fr&7
  const int rk0 = (g ^ (fr & 7)) * 8;
  const int rk1 = ((4 + g) ^ (fr & 7)) * 8;

  for (int pass = 0; pass < 2; ++pass) {
    const int qt = pass ? pj : (NQT - 1 - pj);
    const int q0 = qt * 64;
    const int qrow = q0 + wave * 16 + fr;      // this lane's q-row
    const int k8 = g * 8;
    const bf16x8 qf0 = *(const bf16x8*)&Q[(bh + qrow) * DH + k8];
    const bf16x8 qf1 = *(const bf16x8*)&Q[(bh + qrow) * DH + 32 + k8];

    float lsum = 0.f;
    f32x4 oacc[4];
#pragma unroll
    for (int c = 0; c < 4; ++c) oacc[c] = (f32x4){0.f, 0.f, 0.f, 0.f};

    for (int kvb = 0; kvb <= qt; ++kvb) {
      const int kv0 = kvb * 64;
      {
        const u16* kg = &K[(bh + kv0 + sr) * DH + sgc];
        u16x8 ka = *(const u16x8*)kg;
        u16x8 kc = *(const u16x8*)(kg + 32);
        const u16* vg = &Vt[(vbse + sr) * TT + kv0 + sgc];
        u16x8 va = *(const u16x8*)vg;
        u16x8 vc = *(const u16x8*)(vg + 32);
        *(u16x8*)&Ks[sr * 64 + sw1] = ka;
        *(u16x8*)&Ks[sr * 64 + sw2] = kc;
        *(u16x8*)&Vs[sr * 64 + sw1] = va;
        *(u16x8*)&Vs[sr * 64 + sw2] = vc;
      }
      __syncthreads();

      // S^T = K Q  (log2 domain; scale folded into Q)
      f32x4 s[4];
      __builtin_amdgcn_s_setprio(1);
#pragma unroll
      for (int c = 0; c < 4; ++c) {
        bf16x8 kb0 = *(const bf16x8*)&Ks[(c * 16 + fr) * 64 + rk0];
        bf16x8 kb1 = *(const bf16x8*)&Ks[(c * 16 + fr) * 64 + rk1];
        f32x4 t = (f32x4){0.f, 0.f, 0.f, 0.f};
        t = __builtin_amdgcn_mfma_f32_16x16x32_bf16(kb0, qf0, t, 0, 0, 0);
        t = __builtin_amdgcn_mfma_f32_16x16x32_bf16(kb1, qf1, t, 0, 0, 0);
        s[c] = t;
      }
      __builtin_amdgcn_s_setprio(0);

      if (kvb == qt) {  // diagonal tile: causal mask (in-lane, row = qrow)
#pragma unroll
        for (int c = 0; c < 4; ++c) {
          const int colg = kv0 + c * 16 + 4 * g;
#pragma unroll
          for (int r = 0; r < 4; ++r)
            if (colg + r > qrow) s[c][r] = -1e30f;
        }
      }

      // p = exp2(s), packed in-register; row-sum
      float rs = 0.f;
      uint32_t pk[8];
#pragma unroll
      for (int c = 0; c < 4; ++c) {
        float p0 = __builtin_amdgcn_exp2f(s[c][0]);
        float p1 = __builtin_amdgcn_exp2f(s[c][1]);
        float p2 = __builtin_amdgcn_exp2f(s[c][2]);
        float p3 = __builtin_amdgcn_exp2f(s[c][3]);
        rs += (p0 + p1) + (p2 + p3);
        pk[2 * c] = cvtpk(p0, p1);
        pk[2 * c + 1] = cvtpk(p2, p3);
      }
      rs += __shfl_xor(rs, 16);
      rs += __shfl_xor(rs, 32);
      lsum += rs;

      const bf16x8 pa0 = __builtin_bit_cast(bf16x8, (u32x4){pk[0], pk[1], pk[2], pk[3]});
      const bf16x8 pa1 = __builtin_bit_cast(bf16x8, (u32x4){pk[4], pk[5], pk[6], pk[7]});

      // O^T += V^T P^T   (V columns pre-permuted to match pa slots)
      __builtin_amdgcn_s_setprio(1);
#pragma unroll
      for (int c = 0; c < 4; ++c) {
        bf16x8 vb0 = *(const bf16x8*)&Vs[(c * 16 + fr) * 64 + rk0];
        bf16x8 vb1 = *(const bf16x8*)&Vs[(c * 16 + fr) * 64 + rk1];
        oacc[c] = __builtin_amdgcn_mfma_f32_16x16x32_bf16(vb0, pa0, oacc[c], 0, 0, 0);
        oacc[c] = __builtin_amdgcn_mfma_f32_16x16x32_bf16(vb1, pa1, oacc[c], 0, 0, 0);
      }
      __builtin_amdgcn_s_setprio(0);
      __syncthreads();
    }

    // epilogue: lane owns O[qrow][d = c*16 + 4g + r] -> packed ushort4 stores
    const float inv = 1.f / lsum;
#pragma unroll
    for (int c = 0; c < 4; ++c) {
      ushort4 o;
      o.x = f2b(oacc[c][0] * inv);
      o.y = f2b(oacc[c][1] * inv);
      o.z = f2b(oacc[c][2] * inv);
      o.w = f2b(oacc[c][3] * inv);
      *(ushort4*)&O[((size_t)b * TT + qrow) * DM + h * DH + c * 16 + 4 * g] = o;
    }
  }
}

extern "C" void kernel_launch(void* const* d_in, const int* in_sizes, int n_in,
                              void* d_out, int out_size, void* d_ws, size_t ws_size,
                              hipStream_t stream) {
  const float* x  = (const float*)d_in[0];
  const float* Wq = (const float*)d_in[1];
  const float* bq = (const float*)d_in[2];
  const float* Wk = (const float*)d_in[3];
  const float* bk = (const float*)d_in[4];
  const float* Wv = (const float*)d_in[5];
  const float* bv = (const float*)d_in[6];
  const float* Wo = (const float*)d_in[7];
  const float* bo = (const float*)d_in[8];

  char* w = (char*)d_ws;
  u16* xb    = (u16*)w; w += (size_t)MTOT * DM * 2;
  u16* Wqkvb = (u16*)w; w += (size_t)3 * DM * DM * 2;
  u16* Wob   = (u16*)w; w += (size_t)DM * DM * 2;
  u16* Qb    = (u16*)w; w += (size_t)MTOT * DM * 2;
  u16* Kb    = (u16*)w; w += (size_t)MTOT * DM * 2;
  u16* Vtb   = (u16*)w; w += (size_t)MTOT * DM * 2;
  u16* AOb   = (u16*)w; w += (size_t)MTOT * DM * 2;

  cast_all<<<(NX + 4 * NW) / 256, 256, 0, stream>>>(x, Wq, Wk, Wv, Wo, xb, Wqkvb, Wob);

  const float qs = 0.125f * 1.44269504f;  // 1/sqrt(64) * log2(e), folded into Q
  gemm_qkv8<<<384, 512, 0, stream>>>(xb, Wqkvb, bq, bk, bv, Qb, Kb, Vtb, qs);

  attn_fwd<<<1024, 256, 0, stream>>>(Qb, Kb, Vtb, AOb);

  gemm_out<<<dim3(DM / 128, MTOT / 128), 256, 0, stream>>>(AOb, Wob, bo, (float*)d_out);
}

// Round 11
// 161.044 us; speedup vs baseline: 1.3509x; 1.0326x over previous
//
#include <hip/hip_runtime.h>
#include <stdint.h>

#define DM 1024
#define HEADS 16
#define DH 64
#define BQ 4
#define TT 2048
#define MTOT (BQ*TT)  // 8192
#define NQT (TT/64)   // 32 q-tiles per (b,h)

typedef __attribute__((ext_vector_type(8))) __bf16 bf16x8;
typedef __attribute__((ext_vector_type(4))) float f32x4;
typedef __attribute__((ext_vector_type(4))) uint32_t u32x4;
typedef unsigned short u16;
typedef __attribute__((ext_vector_type(8))) unsigned short u16x8;

__device__ __forceinline__ u16 f2b(float f) {
  uint32_t u = __builtin_bit_cast(uint32_t, f);
  u = (u + 0x7fffu + ((u >> 16) & 1u)) >> 16;
  return (u16)u;
}

__device__ __forceinline__ uint32_t cvtpk(float lo, float hi) {
  uint32_t r;
  asm("v_cvt_pk_bf16_f32 %0, %1, %2" : "=v"(r) : "v"(lo), "v"(hi));
  return r;
}

__device__ __forceinline__ void gload_lds16(const u16* g, u16* l) {
  __builtin_amdgcn_global_load_lds(
      (const __attribute__((address_space(1))) void*)g,
      (__attribute__((address_space(3))) void*)l, 16, 0, 0);
}

// ---------------- fused cast: x, Wq|Wk|Wv (contiguous), Wo -> bf16 ----------------
#define NX (MTOT * DM / 4)   // float4s in x
#define NW (DM * DM / 4)     // float4s per weight matrix
__global__ __launch_bounds__(256) void cast_all(const float* __restrict__ x,
                                                const float* __restrict__ Wq,
                                                const float* __restrict__ Wk,
                                                const float* __restrict__ Wv,
                                                const float* __restrict__ Wo,
                                                u16* __restrict__ xb,
                                                u16* __restrict__ wqkvb,
                                                u16* __restrict__ wob) {
  int i = blockIdx.x * 256 + threadIdx.x;
  const float* src; u16* dst;
  if (i < NX)               { src = x;  dst = xb; }
  else if (i < NX + NW)     { src = Wq; dst = wqkvb;          i -= NX; }
  else if (i < NX + 2 * NW) { src = Wk; dst = wqkvb + 4 * NW; i -= NX + NW; }
  else if (i < NX + 3 * NW) { src = Wv; dst = wqkvb + 8 * NW; i -= NX + 2 * NW; }
  else                      { src = Wo; dst = wob;            i -= NX + 3 * NW; }
  float4 v = ((const float4*)src)[i];
  ushort4 o;
  o.x = f2b(v.x); o.y = f2b(v.y); o.z = f2b(v.z); o.w = f2b(v.w);
  ((ushort4*)dst)[i] = o;
}

// ---------------- fused QKV GEMM, 256x256, counted-vmcnt + 2-phase interleave --
// 4-slot LDS ring (BK=32), depth-3 prefetch, vmcnt(4) steady.  Each step now
// splits into two barrier-bracketed phases (m201/m196 fine interleave):
//   P1: 8 ds_reads (A0-3,B0-3 of kt+1) | 16 MFMA (mi0-3, kt) | stage A-half
//   P2: 4 ds_reads (A4-7 of kt+1)      | 16 MFMA (mi4-7, kt) | stage B-half
#define BKq 32
#define NKq (DM / BKq)          // 32 K-tiles
#define SLOT_A (256 * BKq)      // 8192 elems (16KB)
#define SLOT_E (2 * SLOT_A)     // 16384 elems (32KB) per slot

__global__ __launch_bounds__(512, 2) void gemm_qkv8(const u16* __restrict__ A,
                                                    const u16* __restrict__ W,
                                                    const float* __restrict__ bq,
                                                    const float* __restrict__ bk,
                                                    const float* __restrict__ bv,
                                                    u16* __restrict__ Qo,
                                                    u16* __restrict__ Ko,
                                                    u16* __restrict__ Vto,
                                                    float qs) {
  __shared__ u16 lds[4 * SLOT_E];  // 128 KB
  const int tid = threadIdx.x, lane = tid & 63, wave = tid >> 6;
  const int fr = lane & 15, g = lane >> 4;
  const int wm = wave >> 2, wn = wave & 3;

  // T1: bijective XCD swizzle (384 blocks, 384 % 8 == 0)
  int bid = blockIdx.x;
  bid = (bid & 7) * 48 + (bid >> 3);
  const int bx = bid % 12, by = bid / 12;     // bx: n-tile, by: m-tile
  const int m0 = by * 256, n0 = bx * 256;

  const int srow = tid >> 2;                               // 0..127
  const int schunk = (tid & 3) ^ ((tid >> 3) & 3);         // swizzled 16B chunk
  const u16* gA0 = A + (size_t)(m0 + srow) * DM + schunk * 8;
  const u16* gA1 = gA0 + (size_t)128 * DM;
  const u16* gB0 = W + (size_t)(n0 + srow) * DM + schunk * 8;
  const u16* gB1 = gB0 + (size_t)128 * DM;
  const int dA0 = wave * 512;
  const int dA1 = 4096 + wave * 512;
  const int dB0 = SLOT_A + wave * 512;
  const int dB1 = SLOT_A + 4096 + wave * 512;

#define STAGE_Ah(slot, kt) {                                 \
    u16* ls = &lds[(slot) * SLOT_E];                         \
    const int ke = (kt) * BKq;                               \
    gload_lds16(gA0 + ke, ls + dA0);                         \
    gload_lds16(gA1 + ke, ls + dA1); }
#define STAGE_Bh(slot, kt) {                                 \
    u16* ls = &lds[(slot) * SLOT_E];                         \
    const int ke = (kt) * BKq;                               \
    gload_lds16(gB0 + ke, ls + dB0);                         \
    gload_lds16(gB1 + ke, ls + dB1); }

  const int rchunk = (g ^ ((fr >> 1) & 3)) * 8;
  const int offA = (wm * 128 + fr) * 32 + rchunk;           // + mi*512
  const int offB = SLOT_A + (wn * 64 + fr) * 32 + rchunk;   // + ni*512

  f32x4 acc[8][4];
#pragma unroll
  for (int mi = 0; mi < 8; ++mi)
#pragma unroll
    for (int ni = 0; ni < 4; ++ni) acc[mi][ni] = (f32x4){0.f, 0.f, 0.f, 0.f};

  bf16x8 afA[8], bfA[4], afB[8], bfB[4];

#define READ_P1(AFv, BFv, kt) {                              \
    const u16* sl = &lds[((kt) & 3) * SLOT_E];               \
    _Pragma("unroll")                                        \
    for (int mi = 0; mi < 4; ++mi)                           \
      AFv[mi] = *(const bf16x8*)&sl[offA + mi * 512];        \
    _Pragma("unroll")                                        \
    for (int ni = 0; ni < 4; ++ni)                           \
      BFv[ni] = *(const bf16x8*)&sl[offB + ni * 512]; }
#define READ_P2(AFv, kt) {                                   \
    const u16* sl = &lds[((kt) & 3) * SLOT_E];               \
    _Pragma("unroll")                                        \
    for (int mi = 4; mi < 8; ++mi)                           \
      AFv[mi] = *(const bf16x8*)&sl[offA + mi * 512]; }

#define MFMA_P1(AFv, BFv) {                                  \
    __builtin_amdgcn_s_setprio(1);                           \
    _Pragma("unroll")                                        \
    for (int mi = 0; mi < 4; ++mi)                           \
      _Pragma("unroll")                                      \
      for (int ni = 0; ni < 4; ++ni)                         \
        acc[mi][ni] = __builtin_amdgcn_mfma_f32_16x16x32_bf16(AFv[mi], BFv[ni], acc[mi][ni], 0, 0, 0); \
    __builtin_amdgcn_s_setprio(0); }
#define MFMA_P2(AFv, BFv) {                                  \
    __builtin_amdgcn_s_setprio(1);                           \
    _Pragma("unroll")                                        \
    for (int mi = 4; mi < 8; ++mi)                           \
      _Pragma("unroll")                                      \
      for (int ni = 0; ni < 4; ++ni)                         \
        acc[mi][ni] = __builtin_amdgcn_mfma_f32_16x16x32_bf16(AFv[mi], BFv[ni], acc[mi][ni], 0, 0, 0); \
    __builtin_amdgcn_s_setprio(0); }

#define BARQ asm volatile("s_barrier" ::: "memory");
#define WAIT4 asm volatile("s_waitcnt vmcnt(4)" ::: "memory"); BARQ
#define WAIT0 asm volatile("s_waitcnt vmcnt(0)" ::: "memory"); BARQ

  // one full step: wait, 2 phases, optional stage of kt+3
#define STEP(AFc, BFc, AFn, BFn, kt, DO_STAGE) {             \
    WAIT4                                                    \
    READ_P1(AFn, BFn, (kt) + 1)                              \
    MFMA_P1(AFc, BFc)                                        \
    if (DO_STAGE) STAGE_Ah(((kt) + 3) & 3, (kt) + 3)         \
    BARQ                                                     \
    READ_P2(AFn, (kt) + 1)                                   \
    MFMA_P2(AFc, BFc)                                        \
    if (DO_STAGE) STAGE_Bh(((kt) + 3) & 3, (kt) + 3) }

  // prologue: stage 0,1,2; retire stage0; read frags(0)
  STAGE_Ah(0, 0) STAGE_Bh(0, 0)
  STAGE_Ah(1, 1) STAGE_Bh(1, 1)
  STAGE_Ah(2, 2) STAGE_Bh(2, 2)
  asm volatile("s_waitcnt vmcnt(8)" ::: "memory");
  asm volatile("s_barrier" ::: "memory");
  READ_P1(afA, bfA, 0)
  READ_P2(afA, 0)

  for (int kt = 0; kt < NKq - 4; kt += 2) {
    STEP(afA, bfA, afB, bfB, kt, true)
    STEP(afB, bfB, afA, bfA, kt + 1, true)
  }
  STEP(afA, bfA, afB, bfB, NKq - 4, true)   // kt=28, stages 31
  STEP(afB, bfB, afA, bfA, NKq - 3, false)  // kt=29 (WAIT4 retires stage 30)
  // kt=30: drain stage 31
  WAIT0
  READ_P1(afB, bfB, NKq - 1)
  MFMA_P1(afA, bfA)
  BARQ
  READ_P2(afB, NKq - 1)
  MFMA_P2(afA, bfA)
  // kt=31
  MFMA_P1(afB, bfB)
  MFMA_P2(afB, bfB)

  const int g4 = g * 4;
  const int seg = n0 >> 10;
  const int nbase = (n0 & 1023) + wn * 64 + fr;
  if (seg == 0) {
#pragma unroll
    for (int ni = 0; ni < 4; ++ni) {
      const int cgl = nbase + ni * 16;
      const float bb = bq[cgl];
      const int hh = cgl >> 6, d = cgl & 63;
#pragma unroll
      for (int mi = 0; mi < 8; ++mi) {
        const int m = m0 + wm * 128 + mi * 16 + g4;
        const int bi = m >> 11, t = m & 2047;
        u16* dst = &Qo[(((size_t)bi * HEADS + hh) * TT + t) * DH + d];
#pragma unroll
        for (int j = 0; j < 4; ++j)
          dst[(size_t)j * DH] = f2b((acc[mi][ni][j] + bb) * qs);
      }
    }
  } else if (seg == 1) {
#pragma unroll
    for (int ni = 0; ni < 4; ++ni) {
      const int cgl = nbase + ni * 16;
      const float bb = bk[cgl];
      const int hh = cgl >> 6, d = cgl & 63;
#pragma unroll
      for (int mi = 0; mi < 8; ++mi) {
        const int m = m0 + wm * 128 + mi * 16 + g4;
        const int bi = m >> 11, t = m & 2047;
        u16* dst = &Ko[(((size_t)bi * HEADS + hh) * TT + t) * DH + d];
#pragma unroll
        for (int j = 0; j < 4; ++j)
          dst[(size_t)j * DH] = f2b(acc[mi][ni][j] + bb);
      }
    }
  } else {
#pragma unroll
    for (int ni = 0; ni < 4; ++ni) {
      const int cgl = nbase + ni * 16;
      const float bb = bv[cgl];
      const int hh = cgl >> 6, d = cgl & 63;
#pragma unroll
      for (int mi = 0; mi < 8; ++mi) {
        const int t0 = (m0 + wm * 128 + mi * 16 + g4) & 2047;
        const int bi = (m0 + wm * 128 + mi * 16 + g4) >> 11;
        const int w64 = t0 & 63;
        const int pos = (t0 & ~63) | (((w64 >> 5) & 1) << 5) | (((w64 >> 2) & 3) << 3) |
                        (((w64 >> 4) & 1) << 2);
        ushort4 o;
        o.x = f2b(acc[mi][ni][0] + bb);
        o.y = f2b(acc[mi][ni][1] + bb);
        o.z = f2b(acc[mi][ni][2] + bb);
        o.w = f2b(acc[mi][ni][3] + bb);
        *(ushort4*)&Vto[(((size_t)bi * HEADS + hh) * DH + d) * TT + pos] = o;
      }
    }
  }
#undef STAGE_Ah
#undef STAGE_Bh
#undef READ_P1
#undef READ_P2
#undef MFMA_P1
#undef MFMA_P2
#undef STEP
#undef BARQ
#undef WAIT4
#undef WAIT0
}

// ---------------- O-projection GEMM, same template: BM=256 BN=128 BK=32 -------
// 4-slot ring (24KB/slot, 96KB), 3 loads/slot, depth-3 prefetch -> vmcnt(3)
// steady.  Grid 256 blocks = exactly one block-round (no tail).  8 waves 4Mx2N,
// wave tile 64x64.  XCD map: bid>>5 = n-tile, bid&31 = m-tile (per-XCD A 2MB +
// W 2MB = L2 fit).
#define SLOT_OA (256 * 32)           // 8192 elems
#define SLOT_OB (128 * 32)           // 4096 elems
#define SLOT_OE (SLOT_OA + SLOT_OB)  // 12288 elems (24KB)

__global__ __launch_bounds__(512, 2) void gemm_out8(const u16* __restrict__ A,
                                                    const u16* __restrict__ Bw,
                                                    const float* __restrict__ bias,
                                                    float* __restrict__ outp) {
  __shared__ u16 lds[4 * SLOT_OE];  // 96 KB
  const int tid = threadIdx.x, lane = tid & 63, wave = tid >> 6;
  const int fr = lane & 15, g = lane >> 4;
  const int wm = wave >> 1, wn = wave & 1;

  const int bx = blockIdx.x >> 5, by = blockIdx.x & 31;
  const int m0 = by * 256, n0 = bx * 128;

  const int srow = tid >> 2;                               // 0..127
  const int schunk = (tid & 3) ^ ((tid >> 3) & 3);
  const u16* gA0 = A + (size_t)(m0 + srow) * DM + schunk * 8;
  const u16* gA1 = gA0 + (size_t)128 * DM;
  const u16* gB0 = Bw + (size_t)(n0 + srow) * DM + schunk * 8;
  const int dA0 = wave * 512;
  const int dA1 = 4096 + wave * 512;
  const int dB0 = SLOT_OA + wave * 512;

#define STAGEO(slot, kt) {                                   \
    u16* ls = &lds[(slot) * SLOT_OE];                        \
    const int ke = (kt) * 32;                                \
    gload_lds16(gA0 + ke, ls + dA0);                         \
    gload_lds16(gA1 + ke, ls + dA1);                         \
    gload_lds16(gB0 + ke, ls + dB0); }

  const int rchunk = (g ^ ((fr >> 1) & 3)) * 8;
  const int offA = (wm * 64 + fr) * 32 + rchunk;            // + mi*512
  const int offB = SLOT_OA + (wn * 64 + fr) * 32 + rchunk;  // + ni*512

  f32x4 acc[4][4];
#pragma unroll
  for (int mi = 0; mi < 4; ++mi)
#pragma unroll
    for (int ni = 0; ni < 4; ++ni) acc[mi][ni] = (f32x4){0.f, 0.f, 0.f, 0.f};

  bf16x8 afA[4], bfA[4], afB[4], bfB[4];

#define READO(AFv, BFv, kt) {                                \
    const u16* sl = &lds[((kt) & 3) * SLOT_OE];              \
    _Pragma("unroll")                                        \
    for (int mi = 0; mi < 4; ++mi)                           \
      AFv[mi] = *(const bf16x8*)&sl[offA + mi * 512];        \
    _Pragma("unroll")                                        \
    for (int ni = 0; ni < 4; ++ni)                           \
      BFv[ni] = *(const bf16x8*)&sl[offB + ni * 512]; }

#define MFMAO(AFv, BFv) {                                    \
    __builtin_amdgcn_s_setprio(1);                           \
    _Pragma("unroll")                                        \
    for (int mi = 0; mi < 4; ++mi)                           \
      _Pragma("unroll")                                      \
      for (int ni = 0; ni < 4; ++ni)                         \
        acc[mi][ni] = __builtin_amdgcn_mfma_f32_16x16x32_bf16(AFv[mi], BFv[ni], acc[mi][ni], 0, 0, 0); \
    __builtin_amdgcn_s_setprio(0); }

#define OW3 asm volatile("s_waitcnt vmcnt(3)" ::: "memory"); \
            asm volatile("s_barrier" ::: "memory");
#define OW0 asm volatile("s_waitcnt vmcnt(0)" ::: "memory"); \
            asm volatile("s_barrier" ::: "memory");

  STAGEO(0, 0)
  STAGEO(1, 1)
  STAGEO(2, 2)
  asm volatile("s_waitcnt vmcnt(6)" ::: "memory");
  asm volatile("s_barrier" ::: "memory");
  READO(afA, bfA, 0)

  for (int kt = 0; kt < 28; kt += 2) {
    OW3
    READO(afB, bfB, kt + 1)
    MFMAO(afA, bfA)
    STAGEO((kt + 3) & 3, kt + 3)
    OW3
    READO(afA, bfA, kt + 2)
    MFMAO(afB, bfB)
    STAGEO((kt + 4) & 3, kt + 4)
  }
  OW3                      // retires stage 29
  READO(afB, bfB, 29)
  MFMAO(afA, bfA)          // kt=28
  STAGEO(3, 31)
  OW3                      // retires stage 30
  READO(afA, bfA, 30)
  MFMAO(afB, bfB)          // kt=29
  OW0                      // retires stage 31
  READO(afB, bfB, 31)
  MFMAO(afA, bfA)          // kt=30
  MFMAO(afB, bfB)          // kt=31

  const int g4 = g * 4;
#pragma unroll
  for (int mi = 0; mi < 4; ++mi) {
    const int rg = m0 + wm * 64 + mi * 16 + g4;
#pragma unroll
    for (int ni = 0; ni < 4; ++ni) {
      const int cg = n0 + wn * 64 + ni * 16 + fr;
      const float bb = bias[cg];
#pragma unroll
      for (int j = 0; j < 4; ++j)
        outp[(size_t)(rg + j) * DM + cg] = acc[mi][ni][j] + bb;
    }
  }
#undef STAGEO
#undef READO
#undef MFMAO
#undef OW3
#undef OW0
}

// ---------------- flash attention (unchanged from round 10) ----------------
__global__ __launch_bounds__(256) void attn_fwd(const u16* __restrict__ Q,
                                                const u16* __restrict__ K,
                                                const u16* __restrict__ Vt,
                                                u16* __restrict__ O) {
  const int o_ = blockIdx.x;
  const int r_ = o_ & 7, q_ = o_ >> 3;
  const int gidx = r_ * 8 + (q_ >> 4);     // (b,h) group 0..63
  const int pj = q_ & 15;
  const int b = gidx >> 4, h = gidx & 15;
  const int tid = threadIdx.x, lane = tid & 63, wave = tid >> 6;
  __shared__ u16 Ks[64 * 64];       // K rows [kv][d], XOR-swizzled chunks
  __shared__ u16 Vs[64 * 64];       // V^T rows [d][perm-kv], XOR-swizzled chunks

  const size_t bh = ((size_t)b * HEADS + h) * TT;
  const size_t vbse = ((size_t)b * HEADS + h) * DH;
  const int fr = lane & 15, g = lane >> 4;
  const int sr = tid >> 2;                 // staging row 0..63
  const int sc0 = tid & 3;                 // base 16B chunk 0..3

  const int sw1 = (sc0 ^ (sr & 7)) * 8;
  const int sw2 = ((sc0 + 4) ^ (sr & 7)) * 8;
  const int sgc = sc0 * 8;
  const int rk0 = (g ^ (fr & 7)) * 8;
  const int rk1 = ((4 + g) ^ (fr & 7)) * 8;

  for (int pass = 0; pass < 2; ++pass) {
    const int qt = pass ? pj : (NQT - 1 - pj);
    const int q0 = qt * 64;
    const int qrow = q0 + wave * 16 + fr;      // this lane's q-row
    const int k8 = g * 8;
    const bf16x8 qf0 = *(const bf16x8*)&Q[(bh + qrow) * DH + k8];
    const bf16x8 qf1 = *(const bf16x8*)&Q[(bh + qrow) * DH + 32 + k8];

    float lsum = 0.f;
    f32x4 oacc[4];
#pragma unroll
    for (int c = 0; c < 4; ++c) oacc[c] = (f32x4){0.f, 0.f, 0.f, 0.f};

    for (int kvb = 0; kvb <= qt; ++kvb) {
      const int kv0 = kvb * 64;
      {
        const u16* kg = &K[(bh + kv0 + sr) * DH + sgc];
        u16x8 ka = *(const u16x8*)kg;
        u16x8 kc = *(const u16x8*)(kg + 32);
        const u16* vg = &Vt[(vbse + sr) * TT + kv0 + sgc];
        u16x8 va = *(const u16x8*)vg;
        u16x8 vc = *(const u16x8*)(vg + 32);
        *(u16x8*)&Ks[sr * 64 + sw1] = ka;
        *(u16x8*)&Ks[sr * 64 + sw2] = kc;
        *(u16x8*)&Vs[sr * 64 + sw1] = va;
        *(u16x8*)&Vs[sr * 64 + sw2] = vc;
      }
      __syncthreads();

      // S^T = K Q  (log2 domain; scale folded into Q)
      f32x4 s[4];
      __builtin_amdgcn_s_setprio(1);
#pragma unroll
      for (int c = 0; c < 4; ++c) {
        bf16x8 kb0 = *(const bf16x8*)&Ks[(c * 16 + fr) * 64 + rk0];
        bf16x8 kb1 = *(const bf16x8*)&Ks[(c * 16 + fr) * 64 + rk1];
        f32x4 t = (f32x4){0.f, 0.f, 0.f, 0.f};
        t = __builtin_amdgcn_mfma_f32_16x16x32_bf16(kb0, qf0, t, 0, 0, 0);
        t = __builtin_amdgcn_mfma_f32_16x16x32_bf16(kb1, qf1, t, 0, 0, 0);
        s[c] = t;
      }
      __builtin_amdgcn_s_setprio(0);

      if (kvb == qt) {  // diagonal tile: causal mask (in-lane, row = qrow)
#pragma unroll
        for (int c = 0; c < 4; ++c) {
          const int colg = kv0 + c * 16 + 4 * g;
#pragma unroll
          for (int r = 0; r < 4; ++r)
            if (colg + r > qrow) s[c][r] = -1e30f;
        }
      }

      // p = exp2(s), packed in-register; row-sum
      float rs = 0.f;
      uint32_t pk[8];
#pragma unroll
      for (int c = 0; c < 4; ++c) {
        float p0 = __builtin_amdgcn_exp2f(s[c][0]);
        float p1 = __builtin_amdgcn_exp2f(s[c][1]);
        float p2 = __builtin_amdgcn_exp2f(s[c][2]);
        float p3 = __builtin_amdgcn_exp2f(s[c][3]);
        rs += (p0 + p1) + (p2 + p3);
        pk[2 * c] = cvtpk(p0, p1);
        pk[2 * c + 1] = cvtpk(p2, p3);
      }
      rs += __shfl_xor(rs, 16);
      rs += __shfl_xor(rs, 32);
      lsum += rs;

      const bf16x8 pa0 = __builtin_bit_cast(bf16x8, (u32x4){pk[0], pk[1], pk[2], pk[3]});
      const bf16x8 pa1 = __builtin_bit_cast(bf16x8, (u32x4){pk[4], pk[5], pk[6], pk[7]});

      // O^T += V^T P^T   (V columns pre-permuted to match pa slots)
      __builtin_amdgcn_s_setprio(1);
#pragma unroll
      for (int c = 0; c < 4; ++c) {
        bf16x8 vb0 = *(const bf16x8*)&Vs[(c * 16 + fr) * 64 + rk0];
        bf16x8 vb1 = *(const bf16x8*)&Vs[(c * 16 + fr) * 64 + rk1];
        oacc[c] = __builtin_amdgcn_mfma_f32_16x16x32_bf16(vb0, pa0, oacc[c], 0, 0, 0);
        oacc[c] = __builtin_amdgcn_mfma_f32_16x16x32_bf16(vb1, pa1, oacc[c], 0, 0, 0);
      }
      __builtin_amdgcn_s_setprio(0);
      __syncthreads();
    }

    // epilogue: lane owns O[qrow][d = c*16 + 4g + r] -> packed ushort4 stores
    const float inv = 1.f / lsum;
#pragma unroll
    for (int c = 0; c < 4; ++c) {
      ushort4 o;
      o.x = f2b(oacc[c][0] * inv);
      o.y = f2b(oacc[c][1] * inv);
      o.z = f2b(oacc[c][2] * inv);
      o.w = f2b(oacc[c][3] * inv);
      *(ushort4*)&O[((size_t)b * TT + qrow) * DM + h * DH + c * 16 + 4 * g] = o;
    }
  }
}

extern "C" void kernel_launch(void* const* d_in, const int* in_sizes, int n_in,
                              void* d_out, int out_size, void* d_ws, size_t ws_size,
                              hipStream_t stream) {
  const float* x  = (const float*)d_in[0];
  const float* Wq = (const float*)d_in[1];
  const float* bq = (const float*)d_in[2];
  const float* Wk = (const float*)d_in[3];
  const float* bk = (const float*)d_in[4];
  const float* Wv = (const float*)d_in[5];
  const float* bv = (const float*)d_in[6];
  const float* Wo = (const float*)d_in[7];
  const float* bo = (const float*)d_in[8];

  char* w = (char*)d_ws;
  u16* xb    = (u16*)w; w += (size_t)MTOT * DM * 2;
  u16* Wqkvb = (u16*)w; w += (size_t)3 * DM * DM * 2;
  u16* Wob   = (u16*)w; w += (size_t)DM * DM * 2;
  u16* Qb    = (u16*)w; w += (size_t)MTOT * DM * 2;
  u16* Kb    = (u16*)w; w += (size_t)MTOT * DM * 2;
  u16* Vtb   = (u16*)w; w += (size_t)MTOT * DM * 2;
  u16* AOb   = (u16*)w; w += (size_t)MTOT * DM * 2;

  cast_all<<<(NX + 4 * NW) / 256, 256, 0, stream>>>(x, Wq, Wk, Wv, Wo, xb, Wqkvb, Wob);

  const float qs = 0.125f * 1.44269504f;  // 1/sqrt(64) * log2(e), folded into Q
  gemm_qkv8<<<384, 512, 0, stream>>>(xb, Wqkvb, bq, bk, bv, Qb, Kb, Vtb, qs);

  attn_fwd<<<1024, 256, 0, stream>>>(Qb, Kb, Vtb, AOb);

  gemm_out8<<<256, 512, 0, stream>>>(AOb, Wob, bo, (float*)d_out);
}